// Round 1
// baseline (4602.705 us; speedup 1.0000x reference)
//
#include <hip/hip_runtime.h>
#include <hip/hip_bf16.h>
#include <cstddef>

#define B_    2
#define T_    2048
#define DIM_  1024
#define H_    8
#define HD_   128
#define BT_   (B_*T_)           // 4096
#define E3_   (3*H_*HD_)        // 3072
#define F32_EPS_ 1.1920929e-07f

// ---------------- K1: per-matrix mean|w| -> scale (deterministic) ----------------
__global__ __launch_bounds__(256) void absmean_kernel(const float* __restrict__ w, float* __restrict__ scales) {
    int m = blockIdx.x;                 // 0..3
    const float* wm = w + (size_t)m * (DIM_*DIM_);
    __shared__ float red[256];
    int tid = threadIdx.x;
    float acc = 0.f;
    for (int i = tid; i < DIM_*DIM_; i += 256) acc += fabsf(wm[i]);
    red[tid] = acc; __syncthreads();
    for (int s = 128; s > 0; s >>= 1) { if (tid < s) red[tid] += red[tid+s]; __syncthreads(); }
    if (tid == 0) scales[m] = fmaxf(red[0] / (float)(DIM_*DIM_), 1e-5f);
}

// ---------------- K2: ternary-quantize all 4 weight matrices ----------------
__global__ __launch_bounds__(256) void quant_w_kernel(const float* __restrict__ w, const float* __restrict__ scales,
                                                      float* __restrict__ wq) {
    int idx = blockIdx.x * 256 + threadIdx.x;       // 0..4M-1
    int m = idx >> 20;
    float s = scales[m];
    float r = rintf(w[idx] / s);
    r = fminf(1.f, fmaxf(-1.f, r));
    wq[idx] = s * r;
}

// ---------------- K3: per-row 8-bit quant of x + gate ----------------
__global__ __launch_bounds__(256) void quant_x_gate_kernel(const float* __restrict__ x, const float* __restrict__ gw,
                                                           float* __restrict__ xq, float* __restrict__ gate) {
    int row = blockIdx.x;               // bt
    const float* xr = x + (size_t)row * DIM_;
    float*      qr = xq + (size_t)row * DIM_;
    __shared__ float red[256];
    __shared__ float x12[12];
    int tid = threadIdx.x;
    float v[4];
    float mn = 1e30f, mx = -1e30f;
    #pragma unroll
    for (int i = 0; i < 4; i++) {
        v[i] = xr[i*256 + tid];
        mn = fminf(mn, v[i]); mx = fmaxf(mx, v[i]);
    }
    red[tid] = mn; __syncthreads();
    for (int s = 128; s > 0; s >>= 1) { if (tid < s) red[tid] = fminf(red[tid], red[tid+s]); __syncthreads(); }
    mn = red[0]; __syncthreads();
    red[tid] = mx; __syncthreads();
    for (int s = 128; s > 0; s >>= 1) { if (tid < s) red[tid] = fmaxf(red[tid], red[tid+s]); __syncthreads(); }
    mx = red[0]; __syncthreads();
    float p = fmaxf(mx, 1e-5f);
    float n = fminf(mn, -1e-5f);
    #pragma unroll
    for (int i = 0; i < 4; i++) {
        int gi = i*256 + tid;
        float xv = v[i];
        float sc = (xv >= 0.f) ? p : n;
        float q = rintf(xv / sc * 127.f) / 127.f * sc;
        qr[gi] = q;
        if (gi < 12) x12[gi] = q;
    }
    __syncthreads();
    if (tid < H_) {
        float acc = 0.f;
        #pragma unroll
        for (int f = 0; f < 12; f++) acc += x12[f] * gw[tid*12 + f];
        gate[(size_t)row * H_ + tid] = 1.f / (1.f + expf(-acc));
    }
}

// ---------------- GEMM: C[m][n] = sum_k A[m][k]*Bm[n][k]  (A MxK, B NxK row-major) ----------------
__global__ __launch_bounds__(256) void gemm_atb_kernel(const float* __restrict__ A, const float* __restrict__ Bm,
                                                       float* __restrict__ C, int M, int N, int K) {
    __shared__ float As[16][68];
    __shared__ float Bs[16][68];
    int bm = blockIdx.y * 64, bn = blockIdx.x * 64;
    int tid = threadIdx.x;
    int tx = tid & 15, ty = tid >> 4;
    float c[4][4] = {};
    for (int k0 = 0; k0 < K; k0 += 16) {
        #pragma unroll
        for (int i = 0; i < 4; i++) {
            int idx = i*256 + tid;
            int mm = idx >> 4, kk = idx & 15;
            As[kk][mm] = A[(size_t)(bm+mm)*K + k0 + kk];
            Bs[kk][mm] = Bm[(size_t)(bn+mm)*K + k0 + kk];
        }
        __syncthreads();
        #pragma unroll
        for (int kk = 0; kk < 16; kk++) {
            float4 a = *(const float4*)&As[kk][ty*4];
            float4 b = *(const float4*)&Bs[kk][tx*4];
            c[0][0] += a.x*b.x; c[0][1] += a.x*b.y; c[0][2] += a.x*b.z; c[0][3] += a.x*b.w;
            c[1][0] += a.y*b.x; c[1][1] += a.y*b.y; c[1][2] += a.y*b.z; c[1][3] += a.y*b.w;
            c[2][0] += a.z*b.x; c[2][1] += a.z*b.y; c[2][2] += a.z*b.z; c[2][3] += a.z*b.w;
            c[3][0] += a.w*b.x; c[3][1] += a.w*b.y; c[3][2] += a.w*b.z; c[3][3] += a.w*b.w;
        }
        __syncthreads();
    }
    #pragma unroll
    for (int i = 0; i < 4; i++)
        #pragma unroll
        for (int j = 0; j < 4; j++)
            C[(size_t)(bm + ty*4 + i)*N + bn + tx*4 + j] = c[i][j];
}

// ---------------- K5: rmsnorm -> rotary -> 8-bit quant for q,k ; v = l0*v + l1*ve ----------------
__global__ __launch_bounds__(128) void qkv_post_kernel(float* __restrict__ qkv, const float* __restrict__ ve,
                                                       const float* __restrict__ lam,
                                                       const float* __restrict__ cosb, const float* __restrict__ sinb) {
    int bt = blockIdx.x;
    int part = blockIdx.y;              // 0..23 : 0-7 q heads, 8-15 k heads, 16-23 v heads
    int d = threadIdx.x;                // 0..127
    float* row = qkv + (size_t)bt * E3_ + (size_t)part * HD_;
    if (part >= 16) {
        int h = part - 16;
        float l0 = lam[0], l1 = lam[1];
        row[d] = l0 * row[d] + l1 * ve[(size_t)bt * DIM_ + h*HD_ + d];
        return;
    }
    int t = bt & (T_ - 1);
    __shared__ float buf[128];
    __shared__ float red[128];
    float x = row[d];
    red[d] = x * x; __syncthreads();
    for (int s = 64; s > 0; s >>= 1) { if (d < s) red[d] += red[d+s]; __syncthreads(); }
    float rms = 1.0f / sqrtf(red[0] / 128.0f + F32_EPS_);
    __syncthreads();
    x *= rms;
    buf[d] = x; __syncthreads();
    // rotary
    int j = d & 63;
    float cc = cosb[(size_t)t*64 + j], ss = sinb[(size_t)t*64 + j];
    float x1 = buf[j], x2 = buf[j + 64];
    float o = (d < 64) ? (x1*cc + x2*ss) : (-x1*ss + x2*cc);
    __syncthreads();
    // 8-bit quant over the 128-row
    red[d] = o; __syncthreads();
    for (int s = 64; s > 0; s >>= 1) { if (d < s) red[d] = fminf(red[d], red[d+s]); __syncthreads(); }
    float mn = red[0]; __syncthreads();
    red[d] = o; __syncthreads();
    for (int s = 64; s > 0; s >>= 1) { if (d < s) red[d] = fmaxf(red[d], red[d+s]); __syncthreads(); }
    float mx = red[0]; __syncthreads();
    float p = fmaxf(mx, 1e-5f);
    float n = fminf(mn, -1e-5f);
    float sc = (o >= 0.f) ? p : n;
    row[d] = rintf(o / sc * 127.f) / 127.f * sc;
}

// ---------------- K6: causal attention, one block per (b,h,qi) ----------------
__global__ __launch_bounds__(256) void attn_kernel(const float* __restrict__ qkv, const float* __restrict__ gate,
                                                   float* __restrict__ y) {
    int qi = blockIdx.x;
    int bh = blockIdx.y;
    int b = bh >> 3, h = bh & 7;
    int tid = threadIdx.x;
    __shared__ float qs[128];
    __shared__ float sc[T_];
    __shared__ float red[256];
    const float* base = qkv + (size_t)b * T_ * E3_;
    if (tid < 128) qs[tid] = base[(size_t)qi * E3_ + h*HD_ + tid];
    __syncthreads();
    int nk = qi + 1;
    for (int k = tid; k < nk; k += 256) {
        const float* kr = base + (size_t)k * E3_ + DIM_ + h*HD_;
        float acc = 0.f;
        #pragma unroll 8
        for (int dd = 0; dd < 128; dd++) acc += qs[dd] * kr[dd];
        sc[k] = 0.12f * acc;
    }
    __syncthreads();
    float m = -1e30f;
    for (int k = tid; k < nk; k += 256) m = fmaxf(m, sc[k]);
    red[tid] = m; __syncthreads();
    for (int s = 128; s > 0; s >>= 1) { if (tid < s) red[tid] = fmaxf(red[tid], red[tid+s]); __syncthreads(); }
    m = red[0]; __syncthreads();
    float lsum = 0.f;
    for (int k = tid; k < nk; k += 256) { float e = expf(sc[k] - m); sc[k] = e; lsum += e; }
    red[tid] = lsum; __syncthreads();
    for (int s = 128; s > 0; s >>= 1) { if (tid < s) red[tid] += red[tid+s]; __syncthreads(); }
    float l = red[0]; __syncthreads();
    if (tid < 128) {
        float acc = 0.f;
        const float* vb = base + 2*DIM_ + h*HD_ + tid;
        for (int k = 0; k < nk; k++) acc += sc[k] * vb[(size_t)k * E3_];
        float g = gate[(size_t)(b*T_ + qi) * H_ + h];
        y[(size_t)(b*T_ + qi) * DIM_ + h*HD_ + tid] = acc * g / l;
    }
}

extern "C" void kernel_launch(void* const* d_in, const int* in_sizes, int n_in,
                              void* d_out, int out_size, void* d_ws, size_t ws_size,
                              hipStream_t stream) {
    const float* x    = (const float*)d_in[0];
    const float* ve   = (const float*)d_in[1];
    const float* lam  = (const float*)d_in[2];
    const float* cosb = (const float*)d_in[3];
    const float* sinb = (const float*)d_in[4];
    const float* qkvo = (const float*)d_in[5];
    const float* gw   = (const float*)d_in[6];

    float* wsf    = (float*)d_ws;
    float* scales = wsf;                         // 4 floats (+pad to 16)
    float* XQ     = wsf + 16;                    // 4096*1024
    float* WQ     = XQ + (size_t)BT_*DIM_;       // 4*1024*1024 (qkv rows then w_o)
    float* QKV    = WQ + (size_t)4*DIM_*DIM_;    // 4096*3072
    float* GT     = QKV + (size_t)BT_*E3_;       // 4096*8
    float* Y      = XQ;                          // reuse: xq dead after GEMM1+gate

    absmean_kernel<<<4, 256, 0, stream>>>(qkvo, scales);
    quant_w_kernel<<<(4*DIM_*DIM_)/256, 256, 0, stream>>>(qkvo, scales, WQ);
    quant_x_gate_kernel<<<BT_, 256, 0, stream>>>(x, gw, XQ, GT);
    gemm_atb_kernel<<<dim3(E3_/64, BT_/64), 256, 0, stream>>>(XQ, WQ, QKV, BT_, E3_, DIM_);
    qkv_post_kernel<<<dim3(BT_, 24), 128, 0, stream>>>(QKV, ve, lam, cosb, sinb);
    attn_kernel<<<dim3(T_, B_*H_), 256, 0, stream>>>(QKV, GT, Y);
    gemm_atb_kernel<<<dim3(DIM_/64, BT_/64), 256, 0, stream>>>(Y, WQ + (size_t)3*DIM_*DIM_, (float*)d_out,
                                                               BT_, DIM_, DIM_);
}

// Round 2
// 1615.831 us; speedup vs baseline: 2.8485x; 2.8485x over previous
//
#include <hip/hip_runtime.h>
#include <hip/hip_bf16.h>
#include <cstddef>
#include <cstdint>

#define B_    2
#define T_    2048
#define DIM_  1024
#define H_    8
#define HD_   128
#define BT_   (B_*T_)           // 4096
#define E3_   (3*H_*HD_)        // 3072
#define F32_EPS_ 1.1920929e-07f

typedef __attribute__((ext_vector_type(8))) short bh8_t;
typedef __attribute__((ext_vector_type(4))) float f32x4_t;

__device__ inline unsigned short bf16r(float f) {
    unsigned u = __builtin_bit_cast(unsigned, f);
    u = (u + 0x7fffu + ((u >> 16) & 1u)) >> 16;
    return (unsigned short)u;
}
__device__ inline unsigned bf16pk(float a, float b) {
    return (unsigned)bf16r(a) | ((unsigned)bf16r(b) << 16);
}

// ---------------- K1: per-matrix mean|w| -> scale (deterministic) ----------------
__global__ __launch_bounds__(256) void absmean_kernel(const float* __restrict__ w, float* __restrict__ scales) {
    int m = blockIdx.x;                 // 0..3
    const float* wm = w + (size_t)m * (DIM_*DIM_);
    __shared__ float red[256];
    int tid = threadIdx.x;
    float acc = 0.f;
    for (int i = tid; i < DIM_*DIM_; i += 256) acc += fabsf(wm[i]);
    red[tid] = acc; __syncthreads();
    for (int s = 128; s > 0; s >>= 1) { if (tid < s) red[tid] += red[tid+s]; __syncthreads(); }
    if (tid == 0) scales[m] = fmaxf(red[0] / (float)(DIM_*DIM_), 1e-5f);
}

// ---------------- K2: ternary-quantize all 4 weight matrices (f32 out) ----------------
__global__ __launch_bounds__(256) void quant_w_kernel(const float* __restrict__ w, const float* __restrict__ scales,
                                                      float* __restrict__ wq) {
    int idx = blockIdx.x * 256 + threadIdx.x;       // 0..4M-1
    int m = idx >> 20;
    float s = scales[m];
    float r = rintf(w[idx] / s);
    r = fminf(1.f, fmaxf(-1.f, r));
    wq[idx] = s * r;
}

// ---------------- K3: per-row 8-bit quant of x + gate ----------------
__global__ __launch_bounds__(256) void quant_x_gate_kernel(const float* __restrict__ x, const float* __restrict__ gw,
                                                           float* __restrict__ xq, float* __restrict__ gate) {
    int row = blockIdx.x;               // bt
    const float* xr = x + (size_t)row * DIM_;
    float*      qr = xq + (size_t)row * DIM_;
    __shared__ float red[256];
    __shared__ float x12[12];
    int tid = threadIdx.x;
    float v[4];
    float mn = 1e30f, mx = -1e30f;
    #pragma unroll
    for (int i = 0; i < 4; i++) {
        v[i] = xr[i*256 + tid];
        mn = fminf(mn, v[i]); mx = fmaxf(mx, v[i]);
    }
    red[tid] = mn; __syncthreads();
    for (int s = 128; s > 0; s >>= 1) { if (tid < s) red[tid] = fminf(red[tid], red[tid+s]); __syncthreads(); }
    mn = red[0]; __syncthreads();
    red[tid] = mx; __syncthreads();
    for (int s = 128; s > 0; s >>= 1) { if (tid < s) red[tid] = fmaxf(red[tid], red[tid+s]); __syncthreads(); }
    mx = red[0]; __syncthreads();
    float p = fmaxf(mx, 1e-5f);
    float n = fminf(mn, -1e-5f);
    #pragma unroll
    for (int i = 0; i < 4; i++) {
        int gi = i*256 + tid;
        float xv = v[i];
        float sc = (xv >= 0.f) ? p : n;
        float q = rintf(xv / sc * 127.f) / 127.f * sc;
        qr[gi] = q;
        if (gi < 12) x12[gi] = q;
    }
    __syncthreads();
    if (tid < H_) {
        float acc = 0.f;
        #pragma unroll
        for (int f = 0; f < 12; f++) acc += x12[f] * gw[tid*12 + f];
        gate[(size_t)row * H_ + tid] = 1.f / (1.f + expf(-acc));
    }
}

// ---------------- GEMM (f32): C[m][n] = sum_k A[m][k]*Bm[n][k] ----------------
__global__ __launch_bounds__(256) void gemm_atb_kernel(const float* __restrict__ A, const float* __restrict__ Bm,
                                                       float* __restrict__ C, int M, int N, int K) {
    __shared__ float As[16][68];
    __shared__ float Bs[16][68];
    int bm = blockIdx.y * 64, bn = blockIdx.x * 64;
    int tid = threadIdx.x;
    int tx = tid & 15, ty = tid >> 4;
    float c[4][4] = {};
    for (int k0 = 0; k0 < K; k0 += 16) {
        #pragma unroll
        for (int i = 0; i < 4; i++) {
            int idx = i*256 + tid;
            int mm = idx >> 4, kk = idx & 15;
            As[kk][mm] = A[(size_t)(bm+mm)*K + k0 + kk];
            Bs[kk][mm] = Bm[(size_t)(bn+mm)*K + k0 + kk];
        }
        __syncthreads();
        #pragma unroll
        for (int kk = 0; kk < 16; kk++) {
            float4 a = *(const float4*)&As[kk][ty*4];
            float4 b = *(const float4*)&Bs[kk][tx*4];
            c[0][0] += a.x*b.x; c[0][1] += a.x*b.y; c[0][2] += a.x*b.z; c[0][3] += a.x*b.w;
            c[1][0] += a.y*b.x; c[1][1] += a.y*b.y; c[1][2] += a.y*b.z; c[1][3] += a.y*b.w;
            c[2][0] += a.z*b.x; c[2][1] += a.z*b.y; c[2][2] += a.z*b.z; c[2][3] += a.z*b.w;
            c[3][0] += a.w*b.x; c[3][1] += a.w*b.y; c[3][2] += a.w*b.z; c[3][3] += a.w*b.w;
        }
        __syncthreads();
    }
    #pragma unroll
    for (int i = 0; i < 4; i++)
        #pragma unroll
        for (int j = 0; j < 4; j++)
            C[(size_t)(bm + ty*4 + i)*N + bn + tx*4 + j] = c[i][j];
}

// ---------------- GEMM2 (f32, A stored transposed): C[m][n] = sum_k AT[k][m]*Bm[n][k] ----------------
__global__ __launch_bounds__(256) void gemm_ta_kernel(const float* __restrict__ AT, const float* __restrict__ Bm,
                                                      float* __restrict__ C, int M, int N, int K) {
    __shared__ float As[16][68];
    __shared__ float Bs[16][68];
    int bm = blockIdx.y * 64, bn = blockIdx.x * 64;
    int tid = threadIdx.x;
    int tx = tid & 15, ty = tid >> 4;
    float c[4][4] = {};
    for (int k0 = 0; k0 < K; k0 += 16) {
        {
            int kk = tid >> 4, mm = (tid & 15) * 4;
            float4 v = *(const float4*)(AT + (size_t)(k0+kk)*M + bm + mm);
            *(float4*)&As[kk][mm] = v;
        }
        #pragma unroll
        for (int i = 0; i < 4; i++) {
            int idx = i*256 + tid;
            int mm = idx >> 4, kk = idx & 15;
            Bs[kk][mm] = Bm[(size_t)(bn+mm)*K + k0 + kk];
        }
        __syncthreads();
        #pragma unroll
        for (int kk = 0; kk < 16; kk++) {
            float4 a = *(const float4*)&As[kk][ty*4];
            float4 b = *(const float4*)&Bs[kk][tx*4];
            c[0][0] += a.x*b.x; c[0][1] += a.x*b.y; c[0][2] += a.x*b.z; c[0][3] += a.x*b.w;
            c[1][0] += a.y*b.x; c[1][1] += a.y*b.y; c[1][2] += a.y*b.z; c[1][3] += a.y*b.w;
            c[2][0] += a.z*b.x; c[2][1] += a.z*b.y; c[2][2] += a.z*b.z; c[2][3] += a.z*b.w;
            c[3][0] += a.w*b.x; c[3][1] += a.w*b.y; c[3][2] += a.w*b.z; c[3][3] += a.w*b.w;
        }
        __syncthreads();
    }
    #pragma unroll
    for (int i = 0; i < 4; i++)
        #pragma unroll
        for (int j = 0; j < 4; j++)
            C[(size_t)(bm + ty*4 + i)*N + bn + tx*4 + j] = c[i][j];
}

// ---------------- K5: rmsnorm -> rotary -> quant -> bf16 head-major Q,K ; V mix -> bf16 ----------------
__global__ __launch_bounds__(128) void qkv_post_kernel(const float* __restrict__ qkv, const float* __restrict__ ve,
                                                       const float* __restrict__ lam,
                                                       const float* __restrict__ cosb, const float* __restrict__ sinb,
                                                       unsigned short* __restrict__ Qb, unsigned short* __restrict__ Kb,
                                                       unsigned short* __restrict__ Vb) {
    int bt = blockIdx.x;
    int part = blockIdx.y;              // 0-7 q heads, 8-15 k heads, 16-23 v heads
    int d = threadIdx.x;                // 0..127
    int b = bt >> 11, t = bt & (T_ - 1);
    const float* row = qkv + (size_t)bt * E3_ + (size_t)part * HD_;
    if (part >= 16) {
        int h = part - 16;
        float v = lam[0] * row[d] + lam[1] * ve[(size_t)bt * DIM_ + h*HD_ + d];
        Vb[((size_t)(b*H_ + h) * T_ + t) * HD_ + d] = bf16r(v);
        return;
    }
    __shared__ float buf[128];
    __shared__ float red[128];
    float x = row[d];
    red[d] = x * x; __syncthreads();
    for (int s = 64; s > 0; s >>= 1) { if (d < s) red[d] += red[d+s]; __syncthreads(); }
    float rms = 1.0f / sqrtf(red[0] / 128.0f + F32_EPS_);
    __syncthreads();
    x *= rms;
    buf[d] = x; __syncthreads();
    int j = d & 63;
    float cc = cosb[(size_t)t*64 + j], ss = sinb[(size_t)t*64 + j];
    float x1 = buf[j], x2 = buf[j + 64];
    float o = (d < 64) ? (x1*cc + x2*ss) : (-x1*ss + x2*cc);
    __syncthreads();
    red[d] = o; __syncthreads();
    for (int s = 64; s > 0; s >>= 1) { if (d < s) red[d] = fminf(red[d], red[d+s]); __syncthreads(); }
    float mn = red[0]; __syncthreads();
    red[d] = o; __syncthreads();
    for (int s = 64; s > 0; s >>= 1) { if (d < s) red[d] = fmaxf(red[d], red[d+s]); __syncthreads(); }
    float mx = red[0]; __syncthreads();
    float p = fmaxf(mx, 1e-5f);
    float n = fminf(mn, -1e-5f);
    float sc = (o >= 0.f) ? p : n;
    float q = rintf(o / sc * 127.f) / 127.f * sc;
    if (part < 8) Qb[((size_t)(b*H_ + part) * T_ + t) * HD_ + d] = bf16r(0.12f * q);
    else          Kb[((size_t)(b*H_ + part - 8) * T_ + t) * HD_ + d] = bf16r(q);
}

// ---------------- K6: transpose V (bf16): Vb[bh][t][d] -> VT[bh][d][t] ----------------
__global__ __launch_bounds__(256) void transpose_v_kernel(const unsigned short* __restrict__ Vb,
                                                          unsigned short* __restrict__ VT) {
    int tt = blockIdx.x;            // t tile (64)
    int dt = blockIdx.y;            // d tile (64)
    int bh = blockIdx.z;
    __shared__ unsigned short L[64][80];
    int tid = threadIdx.x;
    #pragma unroll
    for (int i = 0; i < 2; i++) {
        int c = tid + i*256;
        int r = c >> 3, dc = c & 7;
        int4 v = *(const int4*)(Vb + ((size_t)bh*T_ + tt*64 + r)*HD_ + dt*64 + dc*8);
        *(int4*)(&L[r][dc*8]) = v;
    }
    __syncthreads();
    #pragma unroll
    for (int i = 0; i < 2; i++) {
        int c = tid + i*256;
        int r = c >> 3, tc = c & 7;       // r = local d row, tc = t chunk
        unsigned short tmp[8];
        #pragma unroll
        for (int jj = 0; jj < 8; jj++) tmp[jj] = L[tc*8+jj][r];
        *(int4*)(VT + ((size_t)bh*HD_ + dt*64 + r)*T_ + tt*64 + tc*8) = *(const int4*)tmp;
    }
}

// ---------------- K7: flash attention, bf16 MFMA. Writes YT[e][bt] (f32, gated, normalized) ----------------
__global__ __launch_bounds__(256) void attn_kernel(const unsigned short* __restrict__ Qb,
                                                   const unsigned short* __restrict__ Kb,
                                                   const unsigned short* __restrict__ VT,
                                                   const float* __restrict__ gate,
                                                   float* __restrict__ YT) {
    __shared__ unsigned short QS[64*128];
    __shared__ unsigned short KS[64*128];
    __shared__ unsigned short VS[128*64];
    int qt = gridDim.x - 1 - blockIdx.x;        // big q-tiles scheduled first
    int bh = blockIdx.y;
    int b  = bh >> 3, h = bh & 7;
    int tid = threadIdx.x;
    int w = tid >> 6, l = tid & 63;
    int lg = l >> 4, lq = l & 15;

    // ---- stage Q tile (swizzled 16B chunks) ----
    const unsigned short* Qg = Qb + ((size_t)bh*T_ + qt*64) * HD_;
    #pragma unroll
    for (int i = 0; i < 4; i++) {
        int idx = tid + i*256;
        int r = idx >> 4, c = idx & 15;
        int4 v = *(const int4*)(Qg + r*128 + c*8);
        *(int4*)(QS + r*128 + ((c ^ (r & 7)) * 8)) = v;
    }
    __syncthreads();

    // ---- hoist Q fragments (B-frag: lane reads Q row lq at d = kd*32 + lg*8) ----
    int qrow = w*16 + lq;
    int qglob = qt*64 + qrow;
    bh8_t qf[4];
    #pragma unroll
    for (int kd = 0; kd < 4; kd++) {
        int c = kd*4 + lg;
        qf[kd] = *(const bh8_t*)(QS + qrow*128 + ((c ^ (qrow & 7)) * 8));
    }

    f32x4_t o[8];
    #pragma unroll
    for (int dt = 0; dt < 8; dt++) o[dt] = (f32x4_t)0.f;
    float mrun = -1e30f, lrun = 0.f;

    const unsigned short* Kbase = Kb + (size_t)bh*T_*HD_;
    const unsigned short* Vbase = VT + (size_t)bh*HD_*T_;

    for (int kv = 0; kv <= qt; kv++) {
        __syncthreads();
        // stage K tile [64][128]
        #pragma unroll
        for (int i = 0; i < 4; i++) {
            int idx = tid + i*256;
            int r = idx >> 4, c = idx & 15;
            int4 v = *(const int4*)(Kbase + ((size_t)kv*64 + r)*128 + c*8);
            *(int4*)(KS + r*128 + ((c ^ (r & 7)) * 8)) = v;
        }
        // stage V^T tile [128][64]
        #pragma unroll
        for (int i = 0; i < 4; i++) {
            int idx = tid + i*256;
            int r = idx >> 3, c = idx & 7;
            int4 v = *(const int4*)(Vbase + (size_t)r*T_ + kv*64 + c*8);
            *(int4*)(VS + r*64 + ((c ^ (r & 7)) * 8)) = v;
        }
        __syncthreads();

        // ---- S^T[key][q] = K @ Q^T ----
        f32x4_t s[4];
        #pragma unroll
        for (int mt = 0; mt < 4; mt++) {
            s[mt] = (f32x4_t)0.f;
            int krow = mt*16 + lq;
            #pragma unroll
            for (int kd = 0; kd < 4; kd++) {
                int c = kd*4 + lg;
                bh8_t kf = *(const bh8_t*)(KS + krow*128 + ((c ^ (krow & 7)) * 8));
                s[mt] = __builtin_amdgcn_mfma_f32_16x16x32_bf16(kf, qf[kd], s[mt], 0, 0, 0);
            }
        }
        // causal mask on diagonal tile (reg r holds key = kv*64 + mt*16 + lg*4 + r, col q = lq)
        if (kv == qt) {
            #pragma unroll
            for (int mt = 0; mt < 4; mt++)
                #pragma unroll
                for (int r = 0; r < 4; r++) {
                    int key = kv*64 + mt*16 + lg*4 + r;
                    if (key > qglob) s[mt][r] = -1e30f;
                }
        }
        // ---- online softmax (stats per q = lq, reduced over lane groups) ----
        float tm = -1e30f;
        #pragma unroll
        for (int mt = 0; mt < 4; mt++)
            #pragma unroll
            for (int r = 0; r < 4; r++) tm = fmaxf(tm, s[mt][r]);
        tm = fmaxf(tm, __shfl_xor(tm, 16));
        tm = fmaxf(tm, __shfl_xor(tm, 32));
        float mnew = fmaxf(mrun, tm);
        float scale = __expf(mrun - mnew);
        float ls = 0.f;
        unsigned plo[4], phi[4];
        #pragma unroll
        for (int mt = 0; mt < 4; mt++) {
            float p0 = __expf(s[mt][0] - mnew);
            float p1 = __expf(s[mt][1] - mnew);
            float p2 = __expf(s[mt][2] - mnew);
            float p3 = __expf(s[mt][3] - mnew);
            ls += (p0 + p1) + (p2 + p3);
            plo[mt] = bf16pk(p0, p1);
            phi[mt] = bf16pk(p2, p3);
        }
        ls += __shfl_xor(ls, 16);
        ls += __shfl_xor(ls, 32);
        lrun = lrun * scale + ls;
        mrun = mnew;
        #pragma unroll
        for (int dt = 0; dt < 8; dt++) o[dt] *= scale;

        // ---- O^T += V^T @ P^T ----
        int s0 = (lg & 1)*32 + lq;
        int s1 = s0 + 16;
        #pragma unroll
        for (int ks = 0; ks < 2; ks++) {
            unsigned a0 = (unsigned)__shfl((int)plo[2*ks],   s0, 64);
            unsigned a1 = (unsigned)__shfl((int)phi[2*ks],   s0, 64);
            unsigned a2 = (unsigned)__shfl((int)plo[2*ks],   s1, 64);
            unsigned a3 = (unsigned)__shfl((int)phi[2*ks],   s1, 64);
            unsigned b0 = (unsigned)__shfl((int)plo[2*ks+1], s0, 64);
            unsigned b1 = (unsigned)__shfl((int)phi[2*ks+1], s0, 64);
            unsigned b2 = (unsigned)__shfl((int)plo[2*ks+1], s1, 64);
            unsigned b3 = (unsigned)__shfl((int)phi[2*ks+1], s1, 64);
            union { bh8_t v; unsigned u[4]; } pf;
            bool hiHalf = (lg >> 1) != 0;
            pf.u[0] = hiHalf ? b0 : a0;
            pf.u[1] = hiHalf ? b1 : a1;
            pf.u[2] = hiHalf ? b2 : a2;
            pf.u[3] = hiHalf ? b3 : a3;
            #pragma unroll
            for (int dt = 0; dt < 8; dt++) {
                int vrow = dt*16 + lq;
                int c = ks*4 + lg;
                bh8_t vf = *(const bh8_t*)(VS + vrow*64 + ((c ^ (vrow & 7)) * 8));
                o[dt] = __builtin_amdgcn_mfma_f32_16x16x32_bf16(vf, pf.v, o[dt], 0, 0, 0);
            }
        }
    }

    // ---- epilogue: gate, normalize, write YT[e][bt] ----
    float g = gate[((size_t)(b*T_) + qglob) * H_ + h];
    float inv = g / lrun;
    #pragma unroll
    for (int dt = 0; dt < 8; dt++)
        #pragma unroll
        for (int r = 0; r < 4; r++) {
            int d = dt*16 + lg*4 + r;
            YT[(size_t)(h*128 + d) * BT_ + (size_t)b*T_ + qglob] = o[dt][r] * inv;
        }
}

extern "C" void kernel_launch(void* const* d_in, const int* in_sizes, int n_in,
                              void* d_out, int out_size, void* d_ws, size_t ws_size,
                              hipStream_t stream) {
    const float* x    = (const float*)d_in[0];
    const float* ve   = (const float*)d_in[1];
    const float* lam  = (const float*)d_in[2];
    const float* cosb = (const float*)d_in[3];
    const float* sinb = (const float*)d_in[4];
    const float* qkvo = (const float*)d_in[5];
    const float* gw   = (const float*)d_in[6];

    float* wsf    = (float*)d_ws;
    float* scales = wsf;                                   // 16 floats
    float* XQ     = wsf + 16;                              // 4096*1024 f32 (also Vb region, later YT)
    float* WQ     = XQ + (size_t)BT_*DIM_;                 // 4*1024*1024 f32
    float* QKV    = WQ + (size_t)4*DIM_*DIM_;              // 4096*3072 f32
    float* GT     = QKV + (size_t)BT_*E3_;                 // 4096*8 f32
    unsigned short* Qb = (unsigned short*)(GT + (size_t)BT_*H_);      // 16*2048*128 bf16
    unsigned short* Kb = Qb + (size_t)B_*H_*T_*HD_;
    unsigned short* VT = Kb + (size_t)B_*H_*T_*HD_;
    unsigned short* Vb = (unsigned short*)XQ;              // reuse XQ (dead after GEMM1)
    float* YT = XQ;                                        // reuse again after transpose_v

    absmean_kernel<<<4, 256, 0, stream>>>(qkvo, scales);
    quant_w_kernel<<<(4*DIM_*DIM_)/256, 256, 0, stream>>>(qkvo, scales, WQ);
    quant_x_gate_kernel<<<BT_, 256, 0, stream>>>(x, gw, XQ, GT);
    gemm_atb_kernel<<<dim3(E3_/64, BT_/64), 256, 0, stream>>>(XQ, WQ, QKV, BT_, E3_, DIM_);
    qkv_post_kernel<<<dim3(BT_, 24), 128, 0, stream>>>(QKV, ve, lam, cosb, sinb, Qb, Kb, Vb);
    transpose_v_kernel<<<dim3(T_/64, HD_/64, B_*H_), 256, 0, stream>>>(Vb, VT);
    attn_kernel<<<dim3(T_/64, B_*H_), 256, 0, stream>>>(Qb, Kb, VT, GT, YT);
    gemm_ta_kernel<<<dim3(DIM_/64, BT_/64), 256, 0, stream>>>(YT, WQ + (size_t)3*DIM_*DIM_, (float*)d_out,
                                                              BT_, DIM_, DIM_);
}

// Round 3
// 249.034 us; speedup vs baseline: 18.4822x; 6.4884x over previous
//
#include <hip/hip_runtime.h>
#include <hip/hip_bf16.h>
#include <cstddef>
#include <cstdint>

#define B_    2
#define T_    2048
#define DIM_  1024
#define H_    8
#define HD_   128
#define BT_   (B_*T_)           // 4096
#define E3_   (3*H_*HD_)        // 3072
#define F32_EPS_ 1.1920929e-07f

typedef __attribute__((ext_vector_type(8))) short bh8_t;
typedef __attribute__((ext_vector_type(4))) float f32x4_t;
typedef __attribute__((ext_vector_type(4))) unsigned short us4_t;

__device__ inline unsigned short bf16r(float f) {
    unsigned u = __builtin_bit_cast(unsigned, f);
    u = (u + 0x7fffu + ((u >> 16) & 1u)) >> 16;
    return (unsigned short)u;
}
__device__ inline unsigned bf16pk(float a, float b) {
    return (unsigned)bf16r(a) | ((unsigned)bf16r(b) << 16);
}

// ---------------- K1a: per-chunk |w| partial sums (1024 blocks; 256/matrix) ----------------
__global__ __launch_bounds__(256) void absmean1_kernel(const float* __restrict__ w, float* __restrict__ partial) {
    int blk = blockIdx.x;                    // m = blk>>8, chunk = blk&255
    size_t off = (size_t)blk * 4096;
    __shared__ float red[256];
    int tid = threadIdx.x;
    float acc = 0.f;
    const float* p = w + off + tid*16;
    #pragma unroll
    for (int j = 0; j < 4; j++) {
        float4 v = *(const float4*)(p + j*4);
        acc += fabsf(v.x) + fabsf(v.y) + fabsf(v.z) + fabsf(v.w);
    }
    red[tid] = acc; __syncthreads();
    for (int s = 128; s > 0; s >>= 1) { if (tid < s) red[tid] += red[tid+s]; __syncthreads(); }
    if (tid == 0) partial[blk] = red[0];
}

// ---------------- K1b: finalize 4 scales ----------------
__global__ __launch_bounds__(256) void absmean2_kernel(const float* __restrict__ partial, float* __restrict__ scales) {
    int m = blockIdx.x;
    __shared__ float red[256];
    int tid = threadIdx.x;
    red[tid] = partial[m*256 + tid]; __syncthreads();
    for (int s = 128; s > 0; s >>= 1) { if (tid < s) red[tid] += red[tid+s]; __syncthreads(); }
    if (tid == 0) scales[m] = fmaxf(red[0] / (float)(DIM_*DIM_), 1e-5f);
}

// ---------------- K2: ternary-quantize weights -> bf16 {-1,0,+1} ----------------
__global__ __launch_bounds__(256) void quant_w_kernel(const float* __restrict__ w, const float* __restrict__ scales,
                                                      unsigned short* __restrict__ wq) {
    int base = (blockIdx.x * 256 + threadIdx.x) * 8;     // 0..4M-1 step 8
    float s = scales[base >> 20];
    float inv = 1.f / s;
    unsigned short out[8];
    float4 v0 = *(const float4*)(w + base);
    float4 v1 = *(const float4*)(w + base + 4);
    float t[8] = {v0.x, v0.y, v0.z, v0.w, v1.x, v1.y, v1.z, v1.w};
    #pragma unroll
    for (int j = 0; j < 8; j++) {
        float r = rintf(t[j] * inv);
        r = fminf(1.f, fmaxf(-1.f, r));
        out[j] = (r == 0.f) ? 0 : (r > 0.f ? 0x3F80 : 0xBF80);
    }
    *(int4*)(wq + base) = *(const int4*)out;
}

// ---------------- K3: per-row 8-bit quant of x (bf16 out) + gate ----------------
__global__ __launch_bounds__(256) void quant_x_gate_kernel(const float* __restrict__ x, const float* __restrict__ gw,
                                                           unsigned short* __restrict__ xqb, float* __restrict__ gate) {
    int row = blockIdx.x;               // bt
    const float* xr = x + (size_t)row * DIM_;
    unsigned short* qr = xqb + (size_t)row * DIM_;
    __shared__ float red[256];
    __shared__ float x12[12];
    int tid = threadIdx.x;
    float v[4];
    float mn = 1e30f, mx = -1e30f;
    #pragma unroll
    for (int i = 0; i < 4; i++) {
        v[i] = xr[i*256 + tid];
        mn = fminf(mn, v[i]); mx = fmaxf(mx, v[i]);
    }
    red[tid] = mn; __syncthreads();
    for (int s = 128; s > 0; s >>= 1) { if (tid < s) red[tid] = fminf(red[tid], red[tid+s]); __syncthreads(); }
    mn = red[0]; __syncthreads();
    red[tid] = mx; __syncthreads();
    for (int s = 128; s > 0; s >>= 1) { if (tid < s) red[tid] = fmaxf(red[tid], red[tid+s]); __syncthreads(); }
    mx = red[0]; __syncthreads();
    float p = fmaxf(mx, 1e-5f);
    float n = fminf(mn, -1e-5f);
    #pragma unroll
    for (int i = 0; i < 4; i++) {
        int gi = i*256 + tid;
        float xv = v[i];
        float sc = (xv >= 0.f) ? p : n;
        float q = rintf(xv / sc * 127.f) / 127.f * sc;
        qr[gi] = bf16r(q);
        if (gi < 12) x12[gi] = q;
    }
    __syncthreads();
    if (tid < H_) {
        float acc = 0.f;
        #pragma unroll
        for (int f = 0; f < 12; f++) acc += x12[f] * gw[tid*12 + f];
        gate[(size_t)row * H_ + tid] = 1.f / (1.f + expf(-acc));
    }
}

// ---------------- bf16 MFMA GEMM: C[m][n] = sw[sbase+(n>>10)] * sum_k A[m][k]*B[n][k] ----------------
// A:[M][K] bf16 row-major, B:[N][K] bf16 row-major. Tiles 128x128xK64, 4 waves (2x2 of 64x64).
__global__ __launch_bounds__(256) void gemm_bf16_kernel(const unsigned short* __restrict__ A,
                                                        const unsigned short* __restrict__ Bm,
                                                        const float* __restrict__ sw, int sbase,
                                                        float* __restrict__ C, int M, int N, int K) {
    __shared__ unsigned short As[128*64];
    __shared__ unsigned short Bs[128*64];
    int bm = blockIdx.y * 128, bn = blockIdx.x * 128;
    int tid = threadIdx.x;
    int w = tid >> 6, l = tid & 63;
    int wr = w >> 1, wc = w & 1;
    int lg = l >> 4, lq = l & 15;
    f32x4_t acc[4][4];
    #pragma unroll
    for (int mt = 0; mt < 4; mt++)
        #pragma unroll
        for (int nt = 0; nt < 4; nt++) acc[mt][nt] = (f32x4_t)0.f;

    int srow = tid >> 3, sc = tid & 7;          // staging: 32 rows/iter, 8 chunks(16B)/row
    for (int k0 = 0; k0 < K; k0 += 64) {
        #pragma unroll
        for (int i = 0; i < 4; i++) {
            int row = srow + i*32;
            int lc = sc ^ (row & 7);            // logical chunk stored at position sc
            int4 va = *(const int4*)(A + (size_t)(bm+row)*K + k0 + (lc<<3));
            int4 vb = *(const int4*)(Bm + (size_t)(bn+row)*K + k0 + (lc<<3));
            *(int4*)(As + row*64 + (sc<<3)) = va;
            *(int4*)(Bs + row*64 + (sc<<3)) = vb;
        }
        __syncthreads();
        #pragma unroll
        for (int kk = 0; kk < 2; kk++) {
            bh8_t af[4], bf[4];
            #pragma unroll
            for (int mt = 0; mt < 4; mt++) {
                int r = wr*64 + mt*16 + lq;
                int j = kk*4 + lg;
                af[mt] = *(const bh8_t*)(As + r*64 + (((j ^ (r & 7)))<<3));
            }
            #pragma unroll
            for (int nt = 0; nt < 4; nt++) {
                int r = wc*64 + nt*16 + lq;
                int j = kk*4 + lg;
                bf[nt] = *(const bh8_t*)(Bs + r*64 + (((j ^ (r & 7)))<<3));
            }
            #pragma unroll
            for (int mt = 0; mt < 4; mt++)
                #pragma unroll
                for (int nt = 0; nt < 4; nt++)
                    acc[mt][nt] = __builtin_amdgcn_mfma_f32_16x16x32_bf16(af[mt], bf[nt], acc[mt][nt], 0, 0, 0);
        }
        __syncthreads();
    }
    #pragma unroll
    for (int nt = 0; nt < 4; nt++) {
        int col = bn + wc*64 + nt*16 + lq;
        float s = sw[sbase + (col >> 10)];
        #pragma unroll
        for (int mt = 0; mt < 4; mt++) {
            int row = bm + wr*64 + mt*16 + lg*4;
            #pragma unroll
            for (int r = 0; r < 4; r++)
                C[(size_t)(row + r)*N + col] = acc[mt][nt][r] * s;
        }
    }
}

// ---------------- K5: rmsnorm -> rotary -> quant -> bf16 head-major Q,K ; V mix -> bf16 ----------------
__global__ __launch_bounds__(128) void qkv_post_kernel(const float* __restrict__ qkv, const float* __restrict__ ve,
                                                       const float* __restrict__ lam,
                                                       const float* __restrict__ cosb, const float* __restrict__ sinb,
                                                       unsigned short* __restrict__ Qb, unsigned short* __restrict__ Kb,
                                                       unsigned short* __restrict__ Vb) {
    int bt = blockIdx.x;
    int part = blockIdx.y;              // 0-7 q heads, 8-15 k heads, 16-23 v heads
    int d = threadIdx.x;                // 0..127
    int b = bt >> 11, t = bt & (T_ - 1);
    const float* row = qkv + (size_t)bt * E3_ + (size_t)part * HD_;
    if (part >= 16) {
        int h = part - 16;
        float v = lam[0] * row[d] + lam[1] * ve[(size_t)bt * DIM_ + h*HD_ + d];
        Vb[((size_t)(b*H_ + h) * T_ + t) * HD_ + d] = bf16r(v);
        return;
    }
    __shared__ float buf[128];
    __shared__ float red[128];
    float x = row[d];
    red[d] = x * x; __syncthreads();
    for (int s = 64; s > 0; s >>= 1) { if (d < s) red[d] += red[d+s]; __syncthreads(); }
    float rms = 1.0f / sqrtf(red[0] / 128.0f + F32_EPS_);
    __syncthreads();
    x *= rms;
    buf[d] = x; __syncthreads();
    int j = d & 63;
    float cc = cosb[(size_t)t*64 + j], ss = sinb[(size_t)t*64 + j];
    float x1 = buf[j], x2 = buf[j + 64];
    float o = (d < 64) ? (x1*cc + x2*ss) : (-x1*ss + x2*cc);
    __syncthreads();
    red[d] = o; __syncthreads();
    for (int s = 64; s > 0; s >>= 1) { if (d < s) red[d] = fminf(red[d], red[d+s]); __syncthreads(); }
    float mn = red[0]; __syncthreads();
    red[d] = o; __syncthreads();
    for (int s = 64; s > 0; s >>= 1) { if (d < s) red[d] = fmaxf(red[d], red[d+s]); __syncthreads(); }
    float mx = red[0]; __syncthreads();
    float p = fmaxf(mx, 1e-5f);
    float n = fminf(mn, -1e-5f);
    float sc = (o >= 0.f) ? p : n;
    float q = rintf(o / sc * 127.f) / 127.f * sc;
    if (part < 8) Qb[((size_t)(b*H_ + part) * T_ + t) * HD_ + d] = bf16r(0.12f * q);
    else          Kb[((size_t)(b*H_ + part - 8) * T_ + t) * HD_ + d] = bf16r(q);
}

// ---------------- K6: transpose V (bf16): Vb[bh][t][d] -> VT[bh][d][t] ----------------
__global__ __launch_bounds__(256) void transpose_v_kernel(const unsigned short* __restrict__ Vb,
                                                          unsigned short* __restrict__ VT) {
    int tt = blockIdx.x;            // t tile (64)
    int dt = blockIdx.y;            // d tile (64)
    int bh = blockIdx.z;
    __shared__ unsigned short L[64][80];
    int tid = threadIdx.x;
    #pragma unroll
    for (int i = 0; i < 2; i++) {
        int c = tid + i*256;
        int r = c >> 3, dc = c & 7;
        int4 v = *(const int4*)(Vb + ((size_t)bh*T_ + tt*64 + r)*HD_ + dt*64 + dc*8);
        *(int4*)(&L[r][dc*8]) = v;
    }
    __syncthreads();
    #pragma unroll
    for (int i = 0; i < 2; i++) {
        int c = tid + i*256;
        int r = c >> 3, tc = c & 7;
        unsigned short tmp[8];
        #pragma unroll
        for (int jj = 0; jj < 8; jj++) tmp[jj] = L[tc*8+jj][r];
        *(int4*)(VT + ((size_t)bh*HD_ + dt*64 + r)*T_ + tt*64 + tc*8) = *(const int4*)tmp;
    }
}

// ---------------- K7: flash attention bf16 MFMA; writes Yb[bt][e] bf16 (gated, normalized) ----------------
__global__ __launch_bounds__(256) void attn_kernel(const unsigned short* __restrict__ Qb,
                                                   const unsigned short* __restrict__ Kb,
                                                   const unsigned short* __restrict__ VT,
                                                   const float* __restrict__ gate,
                                                   unsigned short* __restrict__ Yb) {
    __shared__ unsigned short QS[64*128];
    __shared__ unsigned short KS[64*128];
    __shared__ unsigned short VS[128*64];
    int qt = gridDim.x - 1 - blockIdx.x;        // big q-tiles scheduled first
    int bh = blockIdx.y;
    int b  = bh >> 3, h = bh & 7;
    int tid = threadIdx.x;
    int w = tid >> 6, l = tid & 63;
    int lg = l >> 4, lq = l & 15;

    const unsigned short* Qg = Qb + ((size_t)bh*T_ + qt*64) * HD_;
    #pragma unroll
    for (int i = 0; i < 4; i++) {
        int idx = tid + i*256;
        int r = idx >> 4, c = idx & 15;
        int4 v = *(const int4*)(Qg + r*128 + c*8);
        *(int4*)(QS + r*128 + ((c ^ (r & 7)) * 8)) = v;
    }
    __syncthreads();

    int qrow = w*16 + lq;
    int qglob = qt*64 + qrow;
    bh8_t qf[4];
    #pragma unroll
    for (int kd = 0; kd < 4; kd++) {
        int c = kd*4 + lg;
        qf[kd] = *(const bh8_t*)(QS + qrow*128 + ((c ^ (qrow & 7)) * 8));
    }

    f32x4_t o[8];
    #pragma unroll
    for (int dt = 0; dt < 8; dt++) o[dt] = (f32x4_t)0.f;
    float mrun = -1e30f, lrun = 0.f;

    const unsigned short* Kbase = Kb + (size_t)bh*T_*HD_;
    const unsigned short* Vbase = VT + (size_t)bh*HD_*T_;

    for (int kv = 0; kv <= qt; kv++) {
        __syncthreads();
        #pragma unroll
        for (int i = 0; i < 4; i++) {
            int idx = tid + i*256;
            int r = idx >> 4, c = idx & 15;
            int4 v = *(const int4*)(Kbase + ((size_t)kv*64 + r)*128 + c*8);
            *(int4*)(KS + r*128 + ((c ^ (r & 7)) * 8)) = v;
        }
        #pragma unroll
        for (int i = 0; i < 4; i++) {
            int idx = tid + i*256;
            int r = idx >> 3, c = idx & 7;
            int4 v = *(const int4*)(Vbase + (size_t)r*T_ + kv*64 + c*8);
            *(int4*)(VS + r*64 + ((c ^ (r & 7)) * 8)) = v;
        }
        __syncthreads();

        f32x4_t s[4];
        #pragma unroll
        for (int mt = 0; mt < 4; mt++) {
            s[mt] = (f32x4_t)0.f;
            int krow = mt*16 + lq;
            #pragma unroll
            for (int kd = 0; kd < 4; kd++) {
                int c = kd*4 + lg;
                bh8_t kf = *(const bh8_t*)(KS + krow*128 + ((c ^ (krow & 7)) * 8));
                s[mt] = __builtin_amdgcn_mfma_f32_16x16x32_bf16(kf, qf[kd], s[mt], 0, 0, 0);
            }
        }
        if (kv == qt) {
            #pragma unroll
            for (int mt = 0; mt < 4; mt++)
                #pragma unroll
                for (int r = 0; r < 4; r++) {
                    int key = kv*64 + mt*16 + lg*4 + r;
                    if (key > qglob) s[mt][r] = -1e30f;
                }
        }
        float tm = -1e30f;
        #pragma unroll
        for (int mt = 0; mt < 4; mt++)
            #pragma unroll
            for (int r = 0; r < 4; r++) tm = fmaxf(tm, s[mt][r]);
        tm = fmaxf(tm, __shfl_xor(tm, 16));
        tm = fmaxf(tm, __shfl_xor(tm, 32));
        float mnew = fmaxf(mrun, tm);
        float scale = __expf(mrun - mnew);
        float ls = 0.f;
        unsigned plo[4], phi[4];
        #pragma unroll
        for (int mt = 0; mt < 4; mt++) {
            float p0 = __expf(s[mt][0] - mnew);
            float p1 = __expf(s[mt][1] - mnew);
            float p2 = __expf(s[mt][2] - mnew);
            float p3 = __expf(s[mt][3] - mnew);
            ls += (p0 + p1) + (p2 + p3);
            plo[mt] = bf16pk(p0, p1);
            phi[mt] = bf16pk(p2, p3);
        }
        ls += __shfl_xor(ls, 16);
        ls += __shfl_xor(ls, 32);
        lrun = lrun * scale + ls;
        mrun = mnew;
        #pragma unroll
        for (int dt = 0; dt < 8; dt++) o[dt] *= scale;

        int s0 = (lg & 1)*32 + lq;
        int s1 = s0 + 16;
        #pragma unroll
        for (int ks = 0; ks < 2; ks++) {
            unsigned a0 = (unsigned)__shfl((int)plo[2*ks],   s0, 64);
            unsigned a1 = (unsigned)__shfl((int)phi[2*ks],   s0, 64);
            unsigned a2 = (unsigned)__shfl((int)plo[2*ks],   s1, 64);
            unsigned a3 = (unsigned)__shfl((int)phi[2*ks],   s1, 64);
            unsigned b0 = (unsigned)__shfl((int)plo[2*ks+1], s0, 64);
            unsigned b1 = (unsigned)__shfl((int)phi[2*ks+1], s0, 64);
            unsigned b2 = (unsigned)__shfl((int)plo[2*ks+1], s1, 64);
            unsigned b3 = (unsigned)__shfl((int)phi[2*ks+1], s1, 64);
            union { bh8_t v; unsigned u[4]; } pf;
            bool hiHalf = (lg >> 1) != 0;
            pf.u[0] = hiHalf ? b0 : a0;
            pf.u[1] = hiHalf ? b1 : a1;
            pf.u[2] = hiHalf ? b2 : a2;
            pf.u[3] = hiHalf ? b3 : a3;
            #pragma unroll
            for (int dt = 0; dt < 8; dt++) {
                int vrow = dt*16 + lq;
                int c = ks*4 + lg;
                bh8_t vf = *(const bh8_t*)(VS + vrow*64 + ((c ^ (vrow & 7)) * 8));
                o[dt] = __builtin_amdgcn_mfma_f32_16x16x32_bf16(vf, pf.v, o[dt], 0, 0, 0);
            }
        }
    }

    // ---- epilogue: gate+normalize, LDS-transpose to row-major, coalesced bf16 write ----
    float g = gate[((size_t)(b*T_) + qglob) * H_ + h];
    float inv = g / lrun;
    __syncthreads();
    unsigned short* YS = QS;            // reuse (64 x 128 bf16)
    #pragma unroll
    for (int dt = 0; dt < 8; dt++) {
        us4_t pk;
        #pragma unroll
        for (int r = 0; r < 4; r++) pk[r] = bf16r(o[dt][r] * inv);
        *(us4_t*)(YS + qrow*128 + dt*16 + lg*4) = pk;
    }
    __syncthreads();
    #pragma unroll
    for (int i = 0; i < 4; i++) {
        int idx = tid + i*256;
        int r = idx >> 4, c = idx & 15;
        int4 v = *(const int4*)(YS + r*128 + c*8);
        *(int4*)(Yb + (size_t)(b*T_ + qt*64 + r)*DIM_ + h*HD_ + c*8) = v;
    }
}

extern "C" void kernel_launch(void* const* d_in, const int* in_sizes, int n_in,
                              void* d_out, int out_size, void* d_ws, size_t ws_size,
                              hipStream_t stream) {
    const float* x    = (const float*)d_in[0];
    const float* ve   = (const float*)d_in[1];
    const float* lam  = (const float*)d_in[2];
    const float* cosb = (const float*)d_in[3];
    const float* sinb = (const float*)d_in[4];
    const float* qkvo = (const float*)d_in[5];
    const float* gw   = (const float*)d_in[6];

    char* ws = (char*)d_ws;
    float* scales  = (float*)ws;                          // 16 f32
    float* partial = scales + 16;                         // 1024 f32
    unsigned short* WQb = (unsigned short*)(ws + (1<<13));            // 8 MB  (4 x 1M bf16)
    unsigned short* XQb = WQb + (size_t)4*DIM_*DIM_;                  // 8 MB
    float* QKV = (float*)(XQb + (size_t)BT_*DIM_);                    // 48 MB
    float* GT  = QKV + (size_t)BT_*E3_;                               // 128 KB
    unsigned short* Qb = (unsigned short*)(GT + (size_t)BT_*H_);      // 8 MB
    unsigned short* Kb = Qb + (size_t)B_*H_*T_*HD_;                   // 8 MB
    unsigned short* VT = Kb + (size_t)B_*H_*T_*HD_;                   // 8 MB
    unsigned short* Vb = VT + (size_t)B_*H_*T_*HD_;                   // 8 MB
    unsigned short* Yb = (unsigned short*)QKV;            // reuse QKV (dead after qkv_post)

    absmean1_kernel<<<1024, 256, 0, stream>>>(qkvo, partial);
    absmean2_kernel<<<4, 256, 0, stream>>>(partial, scales);
    quant_w_kernel<<<(4*DIM_*DIM_)/(256*8), 256, 0, stream>>>(qkvo, scales, WQb);
    quant_x_gate_kernel<<<BT_, 256, 0, stream>>>(x, gw, XQb, GT);
    gemm_bf16_kernel<<<dim3(E3_/128, BT_/128), 256, 0, stream>>>(XQb, WQb, scales, 0, QKV, BT_, E3_, DIM_);
    qkv_post_kernel<<<dim3(BT_, 24), 128, 0, stream>>>(QKV, ve, lam, cosb, sinb, Qb, Kb, Vb);
    transpose_v_kernel<<<dim3(T_/64, HD_/64, B_*H_), 256, 0, stream>>>(Vb, VT);
    attn_kernel<<<dim3(T_/64, B_*H_), 256, 0, stream>>>(Qb, Kb, VT, GT, Yb);
    gemm_bf16_kernel<<<dim3(DIM_/128, BT_/128), 256, 0, stream>>>(Yb, WQb + (size_t)3*DIM_*DIM_, scales, 3,
                                                                  (float*)d_out, BT_, DIM_, DIM_);
}

// Round 4
// 204.130 us; speedup vs baseline: 22.5479x; 1.2200x over previous
//
#include <hip/hip_runtime.h>
#include <hip/hip_bf16.h>
#include <cstddef>
#include <cstdint>

#define B_    2
#define T_    2048
#define DIM_  1024
#define H_    8
#define HD_   128
#define BT_   (B_*T_)           // 4096
#define E3_   (3*H_*HD_)        // 3072
#define F32_EPS_ 1.1920929e-07f

typedef __attribute__((ext_vector_type(8))) short bh8_t;
typedef __attribute__((ext_vector_type(4))) float f32x4_t;
typedef __attribute__((ext_vector_type(16))) float f32x16_t;
typedef __attribute__((ext_vector_type(4))) unsigned short us4_t;

__device__ inline unsigned short bf16r(float f) {
    unsigned u = __builtin_bit_cast(unsigned, f);
    u = (u + 0x7fffu + ((u >> 16) & 1u)) >> 16;
    return (unsigned short)u;
}
__device__ inline unsigned bf16pk(float a, float b) {
    return (unsigned)bf16r(a) | ((unsigned)bf16r(b) << 16);
}
__device__ inline void gl16(const unsigned short* g, unsigned short* l) {
    __builtin_amdgcn_global_load_lds((const __attribute__((address_space(1))) void*)g,
                                     (__attribute__((address_space(3))) void*)l, 16, 0, 0);
}

// ---------------- K1a: per-chunk |w| partial sums ----------------
__global__ __launch_bounds__(256) void absmean1_kernel(const float* __restrict__ w, float* __restrict__ partial) {
    int blk = blockIdx.x;
    size_t off = (size_t)blk * 4096;
    __shared__ float red[256];
    int tid = threadIdx.x;
    float acc = 0.f;
    const float* p = w + off + tid*16;
    #pragma unroll
    for (int j = 0; j < 4; j++) {
        float4 v = *(const float4*)(p + j*4);
        acc += fabsf(v.x) + fabsf(v.y) + fabsf(v.z) + fabsf(v.w);
    }
    red[tid] = acc; __syncthreads();
    for (int s = 128; s > 0; s >>= 1) { if (tid < s) red[tid] += red[tid+s]; __syncthreads(); }
    if (tid == 0) partial[blk] = red[0];
}

// ---------------- K1b: finalize 4 scales ----------------
__global__ __launch_bounds__(256) void absmean2_kernel(const float* __restrict__ partial, float* __restrict__ scales) {
    int m = blockIdx.x;
    __shared__ float red[256];
    int tid = threadIdx.x;
    red[tid] = partial[m*256 + tid]; __syncthreads();
    for (int s = 128; s > 0; s >>= 1) { if (tid < s) red[tid] += red[tid+s]; __syncthreads(); }
    if (tid == 0) scales[m] = fmaxf(red[0] / (float)(DIM_*DIM_), 1e-5f);
}

// ---------------- K2: ternary-quantize weights -> bf16 {-1,0,+1} ----------------
__global__ __launch_bounds__(256) void quant_w_kernel(const float* __restrict__ w, const float* __restrict__ scales,
                                                      unsigned short* __restrict__ wq) {
    int base = (blockIdx.x * 256 + threadIdx.x) * 8;
    float s = scales[base >> 20];
    float inv = 1.f / s;
    unsigned short out[8];
    float4 v0 = *(const float4*)(w + base);
    float4 v1 = *(const float4*)(w + base + 4);
    float t[8] = {v0.x, v0.y, v0.z, v0.w, v1.x, v1.y, v1.z, v1.w};
    #pragma unroll
    for (int j = 0; j < 8; j++) {
        float r = rintf(t[j] * inv);
        r = fminf(1.f, fmaxf(-1.f, r));
        out[j] = (r == 0.f) ? 0 : (r > 0.f ? 0x3F80 : 0xBF80);
    }
    *(int4*)(wq + base) = *(const int4*)out;
}

// ---------------- K3: per-row 8-bit quant of x (bf16 out) + gate ----------------
__global__ __launch_bounds__(256) void quant_x_gate_kernel(const float* __restrict__ x, const float* __restrict__ gw,
                                                           unsigned short* __restrict__ xqb, float* __restrict__ gate) {
    int row = blockIdx.x;
    const float* xr = x + (size_t)row * DIM_;
    unsigned short* qr = xqb + (size_t)row * DIM_;
    __shared__ float red[256];
    __shared__ float x12[12];
    int tid = threadIdx.x;
    float v[4];
    float mn = 1e30f, mx = -1e30f;
    #pragma unroll
    for (int i = 0; i < 4; i++) {
        v[i] = xr[i*256 + tid];
        mn = fminf(mn, v[i]); mx = fmaxf(mx, v[i]);
    }
    red[tid] = mn; __syncthreads();
    for (int s = 128; s > 0; s >>= 1) { if (tid < s) red[tid] = fminf(red[tid], red[tid+s]); __syncthreads(); }
    mn = red[0]; __syncthreads();
    red[tid] = mx; __syncthreads();
    for (int s = 128; s > 0; s >>= 1) { if (tid < s) red[tid] = fmaxf(red[tid], red[tid+s]); __syncthreads(); }
    mx = red[0]; __syncthreads();
    float p = fmaxf(mx, 1e-5f);
    float n = fminf(mn, -1e-5f);
    #pragma unroll
    for (int i = 0; i < 4; i++) {
        int gi = i*256 + tid;
        float xv = v[i];
        float sc = (xv >= 0.f) ? p : n;
        float q = rintf(xv / sc * 127.f) / 127.f * sc;
        qr[gi] = bf16r(q);
        if (gi < 12) x12[gi] = q;
    }
    __syncthreads();
    if (tid < H_) {
        float acc = 0.f;
        #pragma unroll
        for (int f = 0; f < 12; f++) acc += x12[f] * gw[tid*12 + f];
        gate[(size_t)row * H_ + tid] = 1.f / (1.f + expf(-acc));
    }
}

// ---------------- bf16 MFMA GEMM ----------------
__global__ __launch_bounds__(256) void gemm_bf16_kernel(const unsigned short* __restrict__ A,
                                                        const unsigned short* __restrict__ Bm,
                                                        const float* __restrict__ sw, int sbase,
                                                        float* __restrict__ C, int M, int N, int K) {
    __shared__ unsigned short As[128*64];
    __shared__ unsigned short Bs[128*64];
    int bm = blockIdx.y * 128, bn = blockIdx.x * 128;
    int tid = threadIdx.x;
    int w = tid >> 6, l = tid & 63;
    int wr = w >> 1, wc = w & 1;
    int lg = l >> 4, lq = l & 15;
    f32x4_t acc[4][4];
    #pragma unroll
    for (int mt = 0; mt < 4; mt++)
        #pragma unroll
        for (int nt = 0; nt < 4; nt++) acc[mt][nt] = (f32x4_t)0.f;

    int srow = tid >> 3, sc = tid & 7;
    for (int k0 = 0; k0 < K; k0 += 64) {
        #pragma unroll
        for (int i = 0; i < 4; i++) {
            int row = srow + i*32;
            int lc = sc ^ (row & 7);
            int4 va = *(const int4*)(A + (size_t)(bm+row)*K + k0 + (lc<<3));
            int4 vb = *(const int4*)(Bm + (size_t)(bn+row)*K + k0 + (lc<<3));
            *(int4*)(As + row*64 + (sc<<3)) = va;
            *(int4*)(Bs + row*64 + (sc<<3)) = vb;
        }
        __syncthreads();
        #pragma unroll
        for (int kk = 0; kk < 2; kk++) {
            bh8_t af[4], bf[4];
            #pragma unroll
            for (int mt = 0; mt < 4; mt++) {
                int r = wr*64 + mt*16 + lq;
                int j = kk*4 + lg;
                af[mt] = *(const bh8_t*)(As + r*64 + (((j ^ (r & 7)))<<3));
            }
            #pragma unroll
            for (int nt = 0; nt < 4; nt++) {
                int r = wc*64 + nt*16 + lq;
                int j = kk*4 + lg;
                bf[nt] = *(const bh8_t*)(Bs + r*64 + (((j ^ (r & 7)))<<3));
            }
            #pragma unroll
            for (int mt = 0; mt < 4; mt++)
                #pragma unroll
                for (int nt = 0; nt < 4; nt++)
                    acc[mt][nt] = __builtin_amdgcn_mfma_f32_16x16x32_bf16(af[mt], bf[nt], acc[mt][nt], 0, 0, 0);
        }
        __syncthreads();
    }
    #pragma unroll
    for (int nt = 0; nt < 4; nt++) {
        int col = bn + wc*64 + nt*16 + lq;
        float s = sw[sbase + (col >> 10)];
        #pragma unroll
        for (int mt = 0; mt < 4; mt++) {
            int row = bm + wr*64 + mt*16 + lg*4;
            #pragma unroll
            for (int r = 0; r < 4; r++)
                C[(size_t)(row + r)*N + col] = acc[mt][nt][r] * s;
        }
    }
}

// ---------------- K5: rmsnorm -> rotary -> quant -> bf16 head-major Q,K ; V mix ----------------
__global__ __launch_bounds__(128) void qkv_post_kernel(const float* __restrict__ qkv, const float* __restrict__ ve,
                                                       const float* __restrict__ lam,
                                                       const float* __restrict__ cosb, const float* __restrict__ sinb,
                                                       unsigned short* __restrict__ Qb, unsigned short* __restrict__ Kb,
                                                       unsigned short* __restrict__ Vb) {
    int bt = blockIdx.x;
    int part = blockIdx.y;
    int d = threadIdx.x;
    int b = bt >> 11, t = bt & (T_ - 1);
    const float* row = qkv + (size_t)bt * E3_ + (size_t)part * HD_;
    if (part >= 16) {
        int h = part - 16;
        float v = lam[0] * row[d] + lam[1] * ve[(size_t)bt * DIM_ + h*HD_ + d];
        Vb[((size_t)(b*H_ + h) * T_ + t) * HD_ + d] = bf16r(v);
        return;
    }
    __shared__ float buf[128];
    __shared__ float red[128];
    float x = row[d];
    red[d] = x * x; __syncthreads();
    for (int s = 64; s > 0; s >>= 1) { if (d < s) red[d] += red[d+s]; __syncthreads(); }
    float rms = 1.0f / sqrtf(red[0] / 128.0f + F32_EPS_);
    __syncthreads();
    x *= rms;
    buf[d] = x; __syncthreads();
    int j = d & 63;
    float cc = cosb[(size_t)t*64 + j], ss = sinb[(size_t)t*64 + j];
    float x1 = buf[j], x2 = buf[j + 64];
    float o = (d < 64) ? (x1*cc + x2*ss) : (-x1*ss + x2*cc);
    __syncthreads();
    red[d] = o; __syncthreads();
    for (int s = 64; s > 0; s >>= 1) { if (d < s) red[d] = fminf(red[d], red[d+s]); __syncthreads(); }
    float mn = red[0]; __syncthreads();
    red[d] = o; __syncthreads();
    for (int s = 64; s > 0; s >>= 1) { if (d < s) red[d] = fmaxf(red[d], red[d+s]); __syncthreads(); }
    float mx = red[0]; __syncthreads();
    float p = fmaxf(mx, 1e-5f);
    float n = fminf(mn, -1e-5f);
    float sc = (o >= 0.f) ? p : n;
    float q = rintf(o / sc * 127.f) / 127.f * sc;
    if (part < 8) Qb[((size_t)(b*H_ + part) * T_ + t) * HD_ + d] = bf16r(0.12f * q);
    else          Kb[((size_t)(b*H_ + part - 8) * T_ + t) * HD_ + d] = bf16r(q);
}

// ---------------- K6: transpose V (bf16): Vb[bh][t][d] -> VT[bh][d][t] ----------------
__global__ __launch_bounds__(256) void transpose_v_kernel(const unsigned short* __restrict__ Vb,
                                                          unsigned short* __restrict__ VT) {
    int tt = blockIdx.x;
    int dt = blockIdx.y;
    int bh = blockIdx.z;
    __shared__ unsigned short L[64][80];
    int tid = threadIdx.x;
    #pragma unroll
    for (int i = 0; i < 2; i++) {
        int c = tid + i*256;
        int r = c >> 3, dc = c & 7;
        int4 v = *(const int4*)(Vb + ((size_t)bh*T_ + tt*64 + r)*HD_ + dt*64 + dc*8);
        *(int4*)(&L[r][dc*8]) = v;
    }
    __syncthreads();
    #pragma unroll
    for (int i = 0; i < 2; i++) {
        int c = tid + i*256;
        int r = c >> 3, tc = c & 7;
        unsigned short tmp[8];
        #pragma unroll
        for (int jj = 0; jj < 8; jj++) tmp[jj] = L[tc*8+jj][r];
        *(int4*)(VT + ((size_t)bh*HD_ + dt*64 + r)*T_ + tt*64 + tc*8) = *(const int4*)tmp;
    }
}

// ---------------- K7: flash attention, 32x32 MFMA, 8 waves = 2 qsub x 4 kv-streams ----------------
__global__ __launch_bounds__(512) void attn_kernel(const unsigned short* __restrict__ Qb,
                                                   const unsigned short* __restrict__ Kb,
                                                   const unsigned short* __restrict__ VT,
                                                   const float* __restrict__ gate,
                                                   unsigned short* __restrict__ Yb) {
    __shared__ __align__(16) unsigned char SMEM[131072];   // KS[2]:64KB | VS[2]:64KB ; reused by merge
    int qt = gridDim.x - 1 - blockIdx.x;        // big q-tiles first
    int bh = blockIdx.y;
    int b = bh >> 3, h = bh & 7;
    int tid = threadIdx.x;
    int w = tid >> 6, l = tid & 63;
    int qsub = w >> 2, qq = w & 3;              // 2 q-subtiles x 4 kv-quarter streams
    int hh = l >> 5, l5 = l & 31;
    int qrow = qsub*32 + l5;
    int qg = qt*64 + qrow;

    const unsigned short* Kbase = Kb + (size_t)bh*T_*HD_;
    const unsigned short* Vbase = VT + (size_t)bh*HD_*T_;
    const unsigned short* Qg = Qb + ((size_t)bh*T_ + (size_t)qt*64) * HD_;

    // Q fragments from global (B-operand: col q=l5, k = ks*16 + hh*8 + e)
    bh8_t qf[8];
    #pragma unroll
    for (int ks = 0; ks < 8; ks++)
        qf[ks] = *(const bh8_t*)(Qg + (size_t)qrow*HD_ + ks*16 + hh*8);

    int nr = (qt + 2) >> 1;                     // rounds of 128 keys

    f32x16_t o0 = (f32x16_t)0.f, o1 = (f32x16_t)0.f, o2 = (f32x16_t)0.f, o3 = (f32x16_t)0.f;
    float mrun = -1e20f, lrun = 0.f;

    // ---- staging: global_load_lds, linear LDS dest, swizzle folded into SOURCE addr ----
#define STAGE(BI, J) { \
    unsigned short* kb_ = (unsigned short*)(SMEM + (BI)*32768); \
    unsigned short* vb_ = (unsigned short*)(SMEM + 65536 + (BI)*32768); \
    _Pragma("unroll") \
    for (int i_ = 0; i_ < 4; i_++) { \
        int ob_ = (i_*8 + w) << 10; \
        int o_  = ob_ + (l << 4); \
        int row_ = o_ >> 8; \
        int scn_ = (o_ >> 4) & 15; \
        int lcn_ = scn_ ^ (row_ & 7); \
        gl16(Kbase + (size_t)((J)*128 + row_)*HD_ + lcn_*8, kb_ + (ob_ >> 1)); \
        gl16(Vbase + (size_t)row_*T_ + (J)*128 + lcn_*8, vb_ + (ob_ >> 1)); \
    } }

    STAGE(0, 0);
    for (int j = 0; j < nr; j++) {
        if (j + 1 < nr) {
            STAGE((j+1) & 1, j+1);
            asm volatile("s_waitcnt vmcnt(8)" ::: "memory");
        } else {
            asm volatile("s_waitcnt vmcnt(0)" ::: "memory");
        }
        __builtin_amdgcn_s_barrier();
        asm volatile("" ::: "memory");
        const unsigned short* kb = (const unsigned short*)(SMEM + (j&1)*32768);
        const unsigned short* vb = (const unsigned short*)(SMEM + 65536 + (j&1)*32768);
        int kvb = j*128 + qq*32;
        if (kvb <= qt*64 + qsub*32 + 31) {
            // ---- S^T(32k x 32q) = K_quarter @ Q^T ----
            f32x16_t s = (f32x16_t)0.f;
            int krow = qq*32 + l5;
            #pragma unroll
            for (int ks = 0; ks < 8; ks++) {
                int c = (ks*2 + hh) ^ (krow & 7);
                bh8_t kf = *(const bh8_t*)(kb + krow*128 + c*8);
                s = __builtin_amdgcn_mfma_f32_32x32x16_bf16(kf, qf[ks], s, 0, 0, 0);
            }
            if (kvb + 31 > qt*64 + qsub*32) {   // diagonal overlap: per-element causal mask
                #pragma unroll
                for (int r = 0; r < 16; r++) {
                    int key = kvb + (r & 3) + 8*(r >> 2) + 4*hh;
                    if (key > qg) s[r] = -1e30f;
                }
            }
            // ---- online softmax with defer-max (THR=8) ----
            float tm = s[0];
            #pragma unroll
            for (int r = 1; r < 16; r++) tm = fmaxf(tm, s[r]);
            tm = fmaxf(tm, __shfl_xor(tm, 32));
            if (!__all(tm - mrun <= 8.f)) {
                float mnew = fmaxf(mrun, tm);
                float scf = __expf(mrun - mnew);
                lrun *= scf;
                o0 *= scf; o1 *= scf; o2 *= scf; o3 *= scf;
                mrun = mnew;
            }
            float p[16]; float ls = 0.f;
            #pragma unroll
            for (int r = 0; r < 16; r++) { p[r] = __expf(s[r] - mrun); ls += p[r]; }
            ls += __shfl_xor(ls, 32);
            lrun += ls;
            // ---- pack P -> bf16 B-frags via lane<->lane+32 exchange ----
            unsigned u0 = bf16pk(p[0], p[1]),   u1 = bf16pk(p[2], p[3]);
            unsigned u2 = bf16pk(p[4], p[5]),   u3 = bf16pk(p[6], p[7]);
            unsigned u4 = bf16pk(p[8], p[9]),   u5 = bf16pk(p[10], p[11]);
            unsigned u6 = bf16pk(p[12], p[13]), u7 = bf16pk(p[14], p[15]);
            unsigned x0 = (unsigned)__shfl_xor((int)u0, 32), x1 = (unsigned)__shfl_xor((int)u1, 32);
            unsigned x2 = (unsigned)__shfl_xor((int)u2, 32), x3 = (unsigned)__shfl_xor((int)u3, 32);
            unsigned x4 = (unsigned)__shfl_xor((int)u4, 32), x5 = (unsigned)__shfl_xor((int)u5, 32);
            unsigned x6 = (unsigned)__shfl_xor((int)u6, 32), x7 = (unsigned)__shfl_xor((int)u7, 32);
            union { bh8_t v; unsigned uu[4]; } B0, B1;
            B0.uu[0] = hh ? x2 : u0;  B0.uu[1] = hh ? x3 : u1;
            B0.uu[2] = hh ? u2 : x0;  B0.uu[3] = hh ? u3 : x1;
            B1.uu[0] = hh ? x6 : u4;  B1.uu[1] = hh ? x7 : u5;
            B1.uu[2] = hh ? u6 : x4;  B1.uu[3] = hh ? u7 : x5;
            // ---- O^T(128d x 32q) += V^T_quarter @ P^T ----
#define PV_STEP(DT, OACC) { \
    int vrow = DT*32 + l5; \
    bh8_t vf0 = *(const bh8_t*)(vb + vrow*128 + (((qq*4 + hh) ^ (vrow & 7))<<3)); \
    OACC = __builtin_amdgcn_mfma_f32_32x32x16_bf16(vf0, B0.v, OACC, 0, 0, 0); \
    bh8_t vf1 = *(const bh8_t*)(vb + vrow*128 + (((qq*4 + 2 + hh) ^ (vrow & 7))<<3)); \
    OACC = __builtin_amdgcn_mfma_f32_32x32x16_bf16(vf1, B1.v, OACC, 0, 0, 0); }
            PV_STEP(0, o0) PV_STEP(1, o1) PV_STEP(2, o2) PV_STEP(3, o3)
#undef PV_STEP
        }
        asm volatile("s_waitcnt lgkmcnt(0)" ::: "memory");
        __builtin_amdgcn_s_barrier();
        asm volatile("" ::: "memory");
    }

    // ---- 4-way stream merge per qsub (LDS reuse), then epilogue ----
    f32x16_t oA[4] = {o0, o1, o2, o3};
    float* OB = (float*)SMEM;                               // 6 streams x 16KB
    float* ML = (float*)(SMEM + 98304);                     // stats
    unsigned short* YS = (unsigned short*)(SMEM + 100352);  // 16KB out-stage
    if (qq != 0) {
        float* obuf = OB + (size_t)(qsub*3 + qq - 1) * 4096;
        #pragma unroll
        for (int dt = 0; dt < 4; dt++)
            #pragma unroll
            for (int g = 0; g < 4; g++) {
                f32x4_t v4;
                #pragma unroll
                for (int e = 0; e < 4; e++) v4[e] = oA[dt][g*4+e];
                int ch = (dt*4 + g) ^ (l & 7);
                *(f32x4_t*)(obuf + l*64 + ch*4) = v4;
            }
        if (hh == 0) {
            ML[((qsub*4 + qq)*32 + l5)*2]     = mrun;
            ML[((qsub*4 + qq)*32 + l5)*2 + 1] = lrun;
        }
    }
    __syncthreads();
    if (qq == 0) {
        #pragma unroll
        for (int st = 1; st < 4; st++) {
            float mb = ML[((qsub*4 + st)*32 + l5)*2];
            float lb = ML[((qsub*4 + st)*32 + l5)*2 + 1];
            float mN = fmaxf(mrun, mb);
            float fa = __expf(mrun - mN), fb = __expf(mb - mN);
            const float* obuf = OB + (size_t)(qsub*3 + st - 1) * 4096;
            #pragma unroll
            for (int dt = 0; dt < 4; dt++)
                #pragma unroll
                for (int g = 0; g < 4; g++) {
                    int ch = (dt*4 + g) ^ (l & 7);
                    f32x4_t v4 = *(const f32x4_t*)(obuf + l*64 + ch*4);
                    #pragma unroll
                    for (int e = 0; e < 4; e++)
                        oA[dt][g*4+e] = oA[dt][g*4+e]*fa + v4[e]*fb;
                }
            lrun = lrun*fa + lb*fb;
            mrun = mN;
        }
        float gv = gate[((size_t)b*T_ + (size_t)qg)*H_ + h];
        float inv = gv / lrun;
        #pragma unroll
        for (int dt = 0; dt < 4; dt++)
            #pragma unroll
            for (int g = 0; g < 4; g++) {
                unsigned short pk4[4];
                #pragma unroll
                for (int e = 0; e < 4; e++) pk4[e] = bf16r(oA[dt][g*4+e] * inv);
                int ch = (dt*4 + g) ^ (qrow & 7);
                *(us4_t*)(YS + (size_t)qrow*128 + ch*8 + hh*4) = *(const us4_t*)pk4;
            }
    }
    __syncthreads();
    #pragma unroll
    for (int i = 0; i < 2; i++) {
        int idx = tid + i*512;
        int r = idx >> 4, scn = idx & 15;
        int lcn = scn ^ (r & 7);
        int4 v = *(const int4*)(YS + (size_t)r*128 + scn*8);
        *(int4*)(Yb + (size_t)(b*T_ + qt*64 + r)*DIM_ + h*HD_ + lcn*8) = v;
    }
#undef STAGE
}

extern "C" void kernel_launch(void* const* d_in, const int* in_sizes, int n_in,
                              void* d_out, int out_size, void* d_ws, size_t ws_size,
                              hipStream_t stream) {
    const float* x    = (const float*)d_in[0];
    const float* ve   = (const float*)d_in[1];
    const float* lam  = (const float*)d_in[2];
    const float* cosb = (const float*)d_in[3];
    const float* sinb = (const float*)d_in[4];
    const float* qkvo = (const float*)d_in[5];
    const float* gw   = (const float*)d_in[6];

    char* ws = (char*)d_ws;
    float* scales  = (float*)ws;
    float* partial = scales + 16;
    unsigned short* WQb = (unsigned short*)(ws + (1<<13));
    unsigned short* XQb = WQb + (size_t)4*DIM_*DIM_;
    float* QKV = (float*)(XQb + (size_t)BT_*DIM_);
    float* GT  = QKV + (size_t)BT_*E3_;
    unsigned short* Qb = (unsigned short*)(GT + (size_t)BT_*H_);
    unsigned short* Kb = Qb + (size_t)B_*H_*T_*HD_;
    unsigned short* VT = Kb + (size_t)B_*H_*T_*HD_;
    unsigned short* Vb = VT + (size_t)B_*H_*T_*HD_;
    unsigned short* Yb = (unsigned short*)QKV;

    absmean1_kernel<<<1024, 256, 0, stream>>>(qkvo, partial);
    absmean2_kernel<<<4, 256, 0, stream>>>(partial, scales);
    quant_w_kernel<<<(4*DIM_*DIM_)/(256*8), 256, 0, stream>>>(qkvo, scales, WQb);
    quant_x_gate_kernel<<<BT_, 256, 0, stream>>>(x, gw, XQb, GT);
    gemm_bf16_kernel<<<dim3(E3_/128, BT_/128), 256, 0, stream>>>(XQb, WQb, scales, 0, QKV, BT_, E3_, DIM_);
    qkv_post_kernel<<<dim3(BT_, 24), 128, 0, stream>>>(QKV, ve, lam, cosb, sinb, Qb, Kb, Vb);
    transpose_v_kernel<<<dim3(T_/64, HD_/64, B_*H_), 256, 0, stream>>>(Vb, VT);
    attn_kernel<<<dim3(T_/64, B_*H_), 512, 0, stream>>>(Qb, Kb, VT, GT, Yb);
    gemm_bf16_kernel<<<dim3(DIM_/128, BT_/128), 256, 0, stream>>>(Yb, WQb + (size_t)3*DIM_*DIM_, scales, 3,
                                                                  (float*)d_out, BT_, DIM_, DIM_);
}

// Round 5
// 152.545 us; speedup vs baseline: 30.1727x; 1.3382x over previous
//
#include <hip/hip_runtime.h>
#include <hip/hip_bf16.h>
#include <cstddef>
#include <cstdint>

#define B_    2
#define T_    2048
#define DIM_  1024
#define H_    8
#define HD_   128
#define BT_   (B_*T_)           // 4096
#define E3_   (3*H_*HD_)        // 3072
#define F32_EPS_ 1.1920929e-07f

typedef __attribute__((ext_vector_type(8))) short bh8_t;
typedef __attribute__((ext_vector_type(4))) float f32x4_t;
typedef __attribute__((ext_vector_type(16))) float f32x16_t;
typedef __attribute__((ext_vector_type(4))) unsigned short us4_t;

__device__ inline unsigned short bf16r(float f) {
    unsigned u = __builtin_bit_cast(unsigned, f);
    u = (u + 0x7fffu + ((u >> 16) & 1u)) >> 16;
    return (unsigned short)u;
}
__device__ inline unsigned bf16pk(float a, float b) {
    return (unsigned)bf16r(a) | ((unsigned)bf16r(b) << 16);
}
__device__ inline void gl16(const unsigned short* g, unsigned short* l) {
    __builtin_amdgcn_global_load_lds((const __attribute__((address_space(1))) void*)g,
                                     (__attribute__((address_space(3))) void*)l, 16, 0, 0);
}

// ---------------- K1a: per-chunk |w| partial sums ----------------
__global__ __launch_bounds__(256) void absmean1_kernel(const float* __restrict__ w, float* __restrict__ partial) {
    int blk = blockIdx.x;
    size_t off = (size_t)blk * 4096;
    __shared__ float red[256];
    int tid = threadIdx.x;
    float acc = 0.f;
    const float* p = w + off + tid*16;
    #pragma unroll
    for (int j = 0; j < 4; j++) {
        float4 v = *(const float4*)(p + j*4);
        acc += fabsf(v.x) + fabsf(v.y) + fabsf(v.z) + fabsf(v.w);
    }
    red[tid] = acc; __syncthreads();
    for (int s = 128; s > 0; s >>= 1) { if (tid < s) red[tid] += red[tid+s]; __syncthreads(); }
    if (tid == 0) partial[blk] = red[0];
}

// ---------------- K1b: finalize 4 scales ----------------
__global__ __launch_bounds__(256) void absmean2_kernel(const float* __restrict__ partial, float* __restrict__ scales) {
    int m = blockIdx.x;
    __shared__ float red[256];
    int tid = threadIdx.x;
    red[tid] = partial[m*256 + tid]; __syncthreads();
    for (int s = 128; s > 0; s >>= 1) { if (tid < s) red[tid] += red[tid+s]; __syncthreads(); }
    if (tid == 0) scales[m] = fmaxf(red[0] / (float)(DIM_*DIM_), 1e-5f);
}

// ---------------- K2: ternary-quantize weights -> bf16 {-1,0,+1} ----------------
__global__ __launch_bounds__(256) void quant_w_kernel(const float* __restrict__ w, const float* __restrict__ scales,
                                                      unsigned short* __restrict__ wq) {
    int base = (blockIdx.x * 256 + threadIdx.x) * 8;
    float s = scales[base >> 20];
    float inv = 1.f / s;
    unsigned short out[8];
    float4 v0 = *(const float4*)(w + base);
    float4 v1 = *(const float4*)(w + base + 4);
    float t[8] = {v0.x, v0.y, v0.z, v0.w, v1.x, v1.y, v1.z, v1.w};
    #pragma unroll
    for (int j = 0; j < 8; j++) {
        float r = rintf(t[j] * inv);
        r = fminf(1.f, fmaxf(-1.f, r));
        out[j] = (r == 0.f) ? 0 : (r > 0.f ? 0x3F80 : 0xBF80);
    }
    *(int4*)(wq + base) = *(const int4*)out;
}

// ---------------- K3: per-row 8-bit quant of x (bf16 out) + gate ----------------
__global__ __launch_bounds__(256) void quant_x_gate_kernel(const float* __restrict__ x, const float* __restrict__ gw,
                                                           unsigned short* __restrict__ xqb, float* __restrict__ gate) {
    int row = blockIdx.x;
    const float* xr = x + (size_t)row * DIM_;
    unsigned short* qr = xqb + (size_t)row * DIM_;
    __shared__ float red[256];
    __shared__ float x12[12];
    int tid = threadIdx.x;
    float v[4];
    float mn = 1e30f, mx = -1e30f;
    #pragma unroll
    for (int i = 0; i < 4; i++) {
        v[i] = xr[i*256 + tid];
        mn = fminf(mn, v[i]); mx = fmaxf(mx, v[i]);
    }
    red[tid] = mn; __syncthreads();
    for (int s = 128; s > 0; s >>= 1) { if (tid < s) red[tid] = fminf(red[tid], red[tid+s]); __syncthreads(); }
    mn = red[0]; __syncthreads();
    red[tid] = mx; __syncthreads();
    for (int s = 128; s > 0; s >>= 1) { if (tid < s) red[tid] = fmaxf(red[tid], red[tid+s]); __syncthreads(); }
    mx = red[0]; __syncthreads();
    float p = fmaxf(mx, 1e-5f);
    float n = fminf(mn, -1e-5f);
    #pragma unroll
    for (int i = 0; i < 4; i++) {
        int gi = i*256 + tid;
        float xv = v[i];
        float sc = (xv >= 0.f) ? p : n;
        float q = rintf(xv / sc * 127.f) / 127.f * sc;
        qr[gi] = bf16r(q);
        if (gi < 12) x12[gi] = q;
    }
    __syncthreads();
    if (tid < H_) {
        float acc = 0.f;
        #pragma unroll
        for (int f = 0; f < 12; f++) acc += x12[f] * gw[tid*12 + f];
        gate[(size_t)row * H_ + tid] = 1.f / (1.f + expf(-acc));
    }
}

// ---------------- bf16 MFMA GEMM (global_load_lds staging, pre-swizzled source) ----------------
__global__ __launch_bounds__(256) void gemm_bf16_kernel(const unsigned short* __restrict__ A,
                                                        const unsigned short* __restrict__ Bm,
                                                        const float* __restrict__ sw, int sbase,
                                                        float* __restrict__ C, int M, int N, int K) {
    __shared__ __align__(16) unsigned short As[128*64];
    __shared__ __align__(16) unsigned short Bs[128*64];
    int bm = blockIdx.y * 128, bn = blockIdx.x * 128;
    int tid = threadIdx.x;
    int w = tid >> 6, l = tid & 63;
    int wr = w >> 1, wc = w & 1;
    int lg = l >> 4, lq = l & 15;
    f32x4_t acc[4][4];
    #pragma unroll
    for (int mt = 0; mt < 4; mt++)
        #pragma unroll
        for (int nt = 0; nt < 4; nt++) acc[mt][nt] = (f32x4_t)0.f;

    for (int k0 = 0; k0 < K; k0 += 64) {
        #pragma unroll
        for (int i = 0; i < 4; i++) {
            int ob = (i*4 + w) << 10;           // wave-uniform byte base in As/Bs
            int o  = ob + (l << 4);
            int row = o >> 7;                   // 128 B per row
            int scn = (o >> 4) & 7;
            int lcn = scn ^ (row & 7);
            gl16(A  + (size_t)(bm+row)*K + k0 + lcn*8, (unsigned short*)As + (ob >> 1));
            gl16(Bm + (size_t)(bn+row)*K + k0 + lcn*8, (unsigned short*)Bs + (ob >> 1));
        }
        __syncthreads();
        #pragma unroll
        for (int kk = 0; kk < 2; kk++) {
            bh8_t af[4], bf[4];
            #pragma unroll
            for (int mt = 0; mt < 4; mt++) {
                int r = wr*64 + mt*16 + lq;
                int j = kk*4 + lg;
                af[mt] = *(const bh8_t*)(As + r*64 + (((j ^ (r & 7)))<<3));
            }
            #pragma unroll
            for (int nt = 0; nt < 4; nt++) {
                int r = wc*64 + nt*16 + lq;
                int j = kk*4 + lg;
                bf[nt] = *(const bh8_t*)(Bs + r*64 + (((j ^ (r & 7)))<<3));
            }
            #pragma unroll
            for (int mt = 0; mt < 4; mt++)
                #pragma unroll
                for (int nt = 0; nt < 4; nt++)
                    acc[mt][nt] = __builtin_amdgcn_mfma_f32_16x16x32_bf16(af[mt], bf[nt], acc[mt][nt], 0, 0, 0);
        }
        __syncthreads();
    }
    #pragma unroll
    for (int nt = 0; nt < 4; nt++) {
        int col = bn + wc*64 + nt*16 + lq;
        float s = sw[sbase + (col >> 10)];
        #pragma unroll
        for (int mt = 0; mt < 4; mt++) {
            int row = bm + wr*64 + mt*16 + lg*4;
            #pragma unroll
            for (int r = 0; r < 4; r++)
                C[(size_t)(row + r)*N + col] = acc[mt][nt][r] * s;
        }
    }
}

// ---------------- K5: rmsnorm/rotary/quant (wave-per-row, shfl reductions, no LDS) ----------------
__global__ __launch_bounds__(256) void qkv_post_kernel(const float* __restrict__ qkv, const float* __restrict__ ve,
                                                       const float* __restrict__ lam,
                                                       const float* __restrict__ cosb, const float* __restrict__ sinb,
                                                       unsigned short* __restrict__ Qb, unsigned short* __restrict__ Kb,
                                                       unsigned short* __restrict__ Vb) {
    int bt = blockIdx.x;
    int b = bt >> 11, t = bt & (T_ - 1);
    int w = threadIdx.x >> 6, l = threadIdx.x & 63;
    const float* base = qkv + (size_t)bt * E3_;
    float l0 = lam[0], l1 = lam[1];
    // v: 8 head-rows, 2 per wave
    #pragma unroll
    for (int i = 0; i < 2; i++) {
        int h = w*2 + i;
        const float* row = base + (16 + h)*HD_;
        const float* ver = ve + (size_t)bt*DIM_ + h*HD_;
        unsigned short* dst = Vb + ((size_t)(b*H_+h)*T_ + t)*HD_;
        dst[l]      = bf16r(l0*row[l]    + l1*ver[l]);
        dst[l + 64] = bf16r(l0*row[l+64] + l1*ver[l+64]);
    }
    // q,k: 16 head-rows, 4 per wave; lane l holds elems (l, l+64) -> rotary lane-local
    float cc = cosb[(size_t)t*64 + l], ss = sinb[(size_t)t*64 + l];
    #pragma unroll
    for (int i = 0; i < 4; i++) {
        int part = w*4 + i;                 // 0..15
        const float* row = base + part*HD_;
        float x1 = row[l], x2 = row[l+64];
        float ssq = x1*x1 + x2*x2;
        #pragma unroll
        for (int off = 1; off < 64; off <<= 1) ssq += __shfl_xor(ssq, off);
        float rms = 1.0f / sqrtf(ssq / 128.0f + F32_EPS_);
        x1 *= rms; x2 *= rms;
        float o1 = x1*cc + x2*ss;
        float o2 = -x1*ss + x2*cc;
        float mn = fminf(o1, o2), mx = fmaxf(o1, o2);
        #pragma unroll
        for (int off = 1; off < 64; off <<= 1) {
            mn = fminf(mn, __shfl_xor(mn, off));
            mx = fmaxf(mx, __shfl_xor(mx, off));
        }
        float p = fmaxf(mx, 1e-5f);
        float n = fminf(mn, -1e-5f);
        float s1 = (o1 >= 0.f) ? p : n;
        float s2 = (o2 >= 0.f) ? p : n;
        float q1 = rintf(o1 / s1 * 127.f) / 127.f * s1;
        float q2 = rintf(o2 / s2 * 127.f) / 127.f * s2;
        if (part < 8) {
            unsigned short* dst = Qb + ((size_t)(b*H_+part)*T_ + t)*HD_;
            dst[l] = bf16r(0.12f * q1); dst[l + 64] = bf16r(0.12f * q2);
        } else {
            unsigned short* dst = Kb + ((size_t)(b*H_+part-8)*T_ + t)*HD_;
            dst[l] = bf16r(q1); dst[l + 64] = bf16r(q2);
        }
    }
}

// ---------------- K6: transpose V (bf16): Vb[bh][t][d] -> VT[bh][d][t] ----------------
__global__ __launch_bounds__(256) void transpose_v_kernel(const unsigned short* __restrict__ Vb,
                                                          unsigned short* __restrict__ VT) {
    int tt = blockIdx.x;
    int dt = blockIdx.y;
    int bh = blockIdx.z;
    __shared__ unsigned short L[64][80];
    int tid = threadIdx.x;
    #pragma unroll
    for (int i = 0; i < 2; i++) {
        int c = tid + i*256;
        int r = c >> 3, dc = c & 7;
        int4 v = *(const int4*)(Vb + ((size_t)bh*T_ + tt*64 + r)*HD_ + dt*64 + dc*8);
        *(int4*)(&L[r][dc*8]) = v;
    }
    __syncthreads();
    #pragma unroll
    for (int i = 0; i < 2; i++) {
        int c = tid + i*256;
        int r = c >> 3, tc = c & 7;
        unsigned short tmp[8];
        #pragma unroll
        for (int jj = 0; jj < 8; jj++) tmp[jj] = L[tc*8+jj][r];
        *(int4*)(VT + ((size_t)bh*HD_ + dt*64 + r)*T_ + tt*64 + tc*8) = *(const int4*)tmp;
    }
}

// ---------------- K7: flash attention, 4 waves = 2 qsub x 2 kv-streams, KVBLK=64, 64KB LDS ----------------
__global__ __launch_bounds__(256) void attn_kernel(const unsigned short* __restrict__ Qb,
                                                   const unsigned short* __restrict__ Kb,
                                                   const unsigned short* __restrict__ VT,
                                                   const float* __restrict__ gate,
                                                   unsigned short* __restrict__ Yb) {
    __shared__ __align__(16) unsigned char SMEM[65536];   // K[2]:2x16KB | V[2]:2x16KB
    int id = blockIdx.x;
    int bh = id & 15;
    int qi = id >> 4;                           // 0..31
    int qt = (qi < 16) ? (31 - qi) : (qi - 16); // pair big with small across the grid halves
    int b = bh >> 3, h = bh & 7;
    int tid = threadIdx.x;
    int w = tid >> 6, l = tid & 63;
    int qsub = w >> 1, qq = w & 1;              // 2 q-subtiles x 2 kv-streams (32 keys each)
    int hh = l >> 5, l5 = l & 31;
    int qrow = qsub*32 + l5;
    int qg = qt*64 + qrow;

    const unsigned short* Kbase = Kb + (size_t)bh*T_*HD_;
    const unsigned short* Vbase = VT + (size_t)bh*HD_*T_;
    const unsigned short* Qg = Qb + ((size_t)bh*T_ + (size_t)qt*64) * HD_;

    bh8_t qf[8];
    #pragma unroll
    for (int ks = 0; ks < 8; ks++)
        qf[ks] = *(const bh8_t*)(Qg + (size_t)qrow*HD_ + ks*16 + hh*8);

    int nr = qt + 1;                            // rounds of 64 keys

    f32x16_t o0 = (f32x16_t)0.f, o1 = (f32x16_t)0.f, o2 = (f32x16_t)0.f, o3 = (f32x16_t)0.f;
    float mrun = -1e20f, lrun = 0.f;

    // stage K[64 rows x 256B] + V^T[128 rows x 128B] per round; linear LDS dest, source pre-swizzled
#define STAGE(BI, J) { \
    unsigned short* kb_ = (unsigned short*)(SMEM + (BI)*16384); \
    unsigned short* vb_ = (unsigned short*)(SMEM + 32768 + (BI)*16384); \
    _Pragma("unroll") \
    for (int i_ = 0; i_ < 4; i_++) { \
        int ob_ = (i_*4 + w) << 10; \
        int o_  = ob_ + (l << 4); \
        int rk_ = o_ >> 8; \
        int lk_ = ((o_ >> 4) & 15) ^ (rk_ & 7); \
        gl16(Kbase + (size_t)((J)*64 + rk_)*HD_ + lk_*8, kb_ + (ob_ >> 1)); \
        int rv_ = o_ >> 7; \
        int lv_ = ((o_ >> 4) & 7) ^ (rv_ & 7); \
        gl16(Vbase + (size_t)rv_*T_ + (J)*64 + lv_*8, vb_ + (ob_ >> 1)); \
    } }

    STAGE(0, 0);
    for (int j = 0; j < nr; j++) {
        if (j + 1 < nr) {
            STAGE((j+1) & 1, j+1);
            asm volatile("s_waitcnt vmcnt(8)" ::: "memory");
        } else {
            asm volatile("s_waitcnt vmcnt(0)" ::: "memory");
        }
        __builtin_amdgcn_s_barrier();
        asm volatile("" ::: "memory");
        const unsigned short* kb = (const unsigned short*)(SMEM + (j&1)*16384);
        const unsigned short* vb = (const unsigned short*)(SMEM + 32768 + (j&1)*16384);
        int kvb = j*64 + qq*32;
        if (kvb <= qt*64 + qsub*32 + 31) {
            // S^T(32k x 32q) = K_half @ Q^T
            f32x16_t s = (f32x16_t)0.f;
            int krow = qq*32 + l5;
            #pragma unroll
            for (int ks = 0; ks < 8; ks++) {
                int c = (ks*2 + hh) ^ (krow & 7);
                bh8_t kf = *(const bh8_t*)(kb + krow*128 + c*8);
                s = __builtin_amdgcn_mfma_f32_32x32x16_bf16(kf, qf[ks], s, 0, 0, 0);
            }
            if (kvb + 31 > qt*64 + qsub*32) {
                #pragma unroll
                for (int r = 0; r < 16; r++) {
                    int key = kvb + (r & 3) + 8*(r >> 2) + 4*hh;
                    if (key > qg) s[r] = -1e30f;
                }
            }
            // online softmax with defer-max (THR=8)
            float tm = s[0];
            #pragma unroll
            for (int r = 1; r < 16; r++) tm = fmaxf(tm, s[r]);
            tm = fmaxf(tm, __shfl_xor(tm, 32));
            if (!__all(tm - mrun <= 8.f)) {
                float mnew = fmaxf(mrun, tm);
                float scf = __expf(mrun - mnew);
                lrun *= scf;
                o0 *= scf; o1 *= scf; o2 *= scf; o3 *= scf;
                mrun = mnew;
            }
            float p[16]; float ls = 0.f;
            #pragma unroll
            for (int r = 0; r < 16; r++) { p[r] = __expf(s[r] - mrun); ls += p[r]; }
            ls += __shfl_xor(ls, 32);
            lrun += ls;
            // pack P -> bf16 B-frags via lane<->lane+32 exchange
            unsigned u0 = bf16pk(p[0], p[1]),   u1 = bf16pk(p[2], p[3]);
            unsigned u2 = bf16pk(p[4], p[5]),   u3 = bf16pk(p[6], p[7]);
            unsigned u4 = bf16pk(p[8], p[9]),   u5 = bf16pk(p[10], p[11]);
            unsigned u6 = bf16pk(p[12], p[13]), u7 = bf16pk(p[14], p[15]);
            unsigned x0 = (unsigned)__shfl_xor((int)u0, 32), x1 = (unsigned)__shfl_xor((int)u1, 32);
            unsigned x2 = (unsigned)__shfl_xor((int)u2, 32), x3 = (unsigned)__shfl_xor((int)u3, 32);
            unsigned x4 = (unsigned)__shfl_xor((int)u4, 32), x5 = (unsigned)__shfl_xor((int)u5, 32);
            unsigned x6 = (unsigned)__shfl_xor((int)u6, 32), x7 = (unsigned)__shfl_xor((int)u7, 32);
            union { bh8_t v; unsigned uu[4]; } B0, B1;
            B0.uu[0] = hh ? x2 : u0;  B0.uu[1] = hh ? x3 : u1;
            B0.uu[2] = hh ? u2 : x0;  B0.uu[3] = hh ? u3 : x1;
            B1.uu[0] = hh ? x6 : u4;  B1.uu[1] = hh ? x7 : u5;
            B1.uu[2] = hh ? u6 : x4;  B1.uu[3] = hh ? u7 : x5;
            // O^T(128d x 32q) += V^T_half @ P^T
#define PV_STEP(DT, OACC) { \
    int vrow = DT*32 + l5; \
    bh8_t vf0 = *(const bh8_t*)(vb + vrow*64 + (((qq*4 + hh) ^ (vrow & 7))<<3)); \
    OACC = __builtin_amdgcn_mfma_f32_32x32x16_bf16(vf0, B0.v, OACC, 0, 0, 0); \
    bh8_t vf1 = *(const bh8_t*)(vb + vrow*64 + (((qq*4 + 2 + hh) ^ (vrow & 7))<<3)); \
    OACC = __builtin_amdgcn_mfma_f32_32x32x16_bf16(vf1, B1.v, OACC, 0, 0, 0); }
            PV_STEP(0, o0) PV_STEP(1, o1) PV_STEP(2, o2) PV_STEP(3, o3)
#undef PV_STEP
        }
        asm volatile("s_waitcnt lgkmcnt(0)" ::: "memory");
        __builtin_amdgcn_s_barrier();
        asm volatile("" ::: "memory");
    }

    // ---- 2-way stream merge per qsub (LDS reuse), then epilogue ----
    f32x16_t oA[4] = {o0, o1, o2, o3};
    float* OB = (float*)SMEM;                               // 2 streams x 16KB
    float* ML = (float*)(SMEM + 32768);                     // stats (512B)
    unsigned short* YS = (unsigned short*)(SMEM + 33280);   // 16KB out-stage
    if (qq != 0) {
        float* obuf = OB + (size_t)qsub * 4096;
        #pragma unroll
        for (int dt = 0; dt < 4; dt++)
            #pragma unroll
            for (int g = 0; g < 4; g++) {
                f32x4_t v4;
                #pragma unroll
                for (int e = 0; e < 4; e++) v4[e] = oA[dt][g*4+e];
                int ch = (dt*4 + g) ^ (l & 7);
                *(f32x4_t*)(obuf + l*64 + ch*4) = v4;
            }
        if (hh == 0) {
            ML[(qsub*32 + l5)*2]     = mrun;
            ML[(qsub*32 + l5)*2 + 1] = lrun;
        }
    }
    __syncthreads();
    if (qq == 0) {
        float mb = ML[(qsub*32 + l5)*2];
        float lb = ML[(qsub*32 + l5)*2 + 1];
        float mN = fmaxf(mrun, mb);
        float fa = __expf(mrun - mN), fb = __expf(mb - mN);
        const float* obuf = OB + (size_t)qsub * 4096;
        #pragma unroll
        for (int dt = 0; dt < 4; dt++)
            #pragma unroll
            for (int g = 0; g < 4; g++) {
                int ch = (dt*4 + g) ^ (l & 7);
                f32x4_t v4 = *(const f32x4_t*)(obuf + l*64 + ch*4);
                #pragma unroll
                for (int e = 0; e < 4; e++)
                    oA[dt][g*4+e] = oA[dt][g*4+e]*fa + v4[e]*fb;
            }
        lrun = lrun*fa + lb*fb;
        float gv = gate[((size_t)b*T_ + (size_t)qg)*H_ + h];
        float inv = gv / lrun;
        #pragma unroll
        for (int dt = 0; dt < 4; dt++)
            #pragma unroll
            for (int g = 0; g < 4; g++) {
                unsigned short pk4[4];
                #pragma unroll
                for (int e = 0; e < 4; e++) pk4[e] = bf16r(oA[dt][g*4+e] * inv);
                int ch = (dt*4 + g) ^ (qrow & 7);
                *(us4_t*)(YS + (size_t)qrow*128 + ch*8 + hh*4) = *(const us4_t*)pk4;
            }
    }
    __syncthreads();
    #pragma unroll
    for (int i = 0; i < 4; i++) {
        int idx = tid + i*256;
        int r = idx >> 4, scn = idx & 15;
        int lcn = scn ^ (r & 7);
        int4 v = *(const int4*)(YS + (size_t)r*128 + scn*8);
        *(int4*)(Yb + (size_t)(b*T_ + qt*64 + r)*DIM_ + h*HD_ + lcn*8) = v;
    }
#undef STAGE
}

extern "C" void kernel_launch(void* const* d_in, const int* in_sizes, int n_in,
                              void* d_out, int out_size, void* d_ws, size_t ws_size,
                              hipStream_t stream) {
    const float* x    = (const float*)d_in[0];
    const float* ve   = (const float*)d_in[1];
    const float* lam  = (const float*)d_in[2];
    const float* cosb = (const float*)d_in[3];
    const float* sinb = (const float*)d_in[4];
    const float* qkvo = (const float*)d_in[5];
    const float* gw   = (const float*)d_in[6];

    char* ws = (char*)d_ws;
    float* scales  = (float*)ws;
    float* partial = scales + 16;
    unsigned short* WQb = (unsigned short*)(ws + (1<<13));
    unsigned short* XQb = WQb + (size_t)4*DIM_*DIM_;
    float* QKV = (float*)(XQb + (size_t)BT_*DIM_);
    float* GT  = QKV + (size_t)BT_*E3_;
    unsigned short* Qb = (unsigned short*)(GT + (size_t)BT_*H_);
    unsigned short* Kb = Qb + (size_t)B_*H_*T_*HD_;
    unsigned short* VT = Kb + (size_t)B_*H_*T_*HD_;
    unsigned short* Vb = VT + (size_t)B_*H_*T_*HD_;
    unsigned short* Yb = (unsigned short*)QKV;

    absmean1_kernel<<<1024, 256, 0, stream>>>(qkvo, partial);
    absmean2_kernel<<<4, 256, 0, stream>>>(partial, scales);
    quant_w_kernel<<<(4*DIM_*DIM_)/(256*8), 256, 0, stream>>>(qkvo, scales, WQb);
    quant_x_gate_kernel<<<BT_, 256, 0, stream>>>(x, gw, XQb, GT);
    gemm_bf16_kernel<<<dim3(E3_/128, BT_/128), 256, 0, stream>>>(XQb, WQb, scales, 0, QKV, BT_, E3_, DIM_);
    qkv_post_kernel<<<BT_, 256, 0, stream>>>(QKV, ve, lam, cosb, sinb, Qb, Kb, Vb);
    transpose_v_kernel<<<dim3(T_/64, HD_/64, B_*H_), 256, 0, stream>>>(Vb, VT);
    attn_kernel<<<512, 256, 0, stream>>>(Qb, Kb, VT, GT, Yb);
    gemm_bf16_kernel<<<dim3(DIM_/128, BT_/128), 256, 0, stream>>>(Yb, WQb + (size_t)3*DIM_*DIM_, scales, 3,
                                                                  (float*)d_out, BT_, DIM_, DIM_);
}

// Round 6
// 145.800 us; speedup vs baseline: 31.5685x; 1.0463x over previous
//
#include <hip/hip_runtime.h>
#include <hip/hip_bf16.h>
#include <cstddef>
#include <cstdint>

#define B_    2
#define T_    2048
#define DIM_  1024
#define H_    8
#define HD_   128
#define BT_   (B_*T_)           // 4096
#define E3_   (3*H_*HD_)        // 3072
#define F32_EPS_ 1.1920929e-07f
#define QSC_  0.17312340490667562f   // 0.12 * log2(e): softmax runs in log2 domain

typedef __attribute__((ext_vector_type(8))) short bh8_t;
typedef __attribute__((ext_vector_type(4))) float f32x4_t;
typedef __attribute__((ext_vector_type(16))) float f32x16_t;
typedef __attribute__((ext_vector_type(4))) unsigned short us4_t;

__device__ inline unsigned short bf16r(float f) {
    unsigned u = __builtin_bit_cast(unsigned, f);
    u = (u + 0x7fffu + ((u >> 16) & 1u)) >> 16;
    return (unsigned short)u;
}
__device__ inline float b2f(unsigned short u) {
    return __builtin_bit_cast(float, (unsigned)u << 16);
}
__device__ inline unsigned cvtpk(float a, float b) {     // 2xf32 -> packed bf16 (lo=a)
    unsigned r;
    asm("v_cvt_pk_bf16_f32 %0, %1, %2" : "=v"(r) : "v"(a), "v"(b));
    return r;
}
__device__ inline void gl16(const unsigned short* g, unsigned short* l) {
    __builtin_amdgcn_global_load_lds((const __attribute__((address_space(1))) void*)g,
                                     (__attribute__((address_space(3))) void*)l, 16, 0, 0);
}

// ---------------- K1a: per-chunk |w| partial sums ----------------
__global__ __launch_bounds__(256) void absmean1_kernel(const float* __restrict__ w, float* __restrict__ partial) {
    int blk = blockIdx.x;
    size_t off = (size_t)blk * 4096;
    __shared__ float red[256];
    int tid = threadIdx.x;
    float acc = 0.f;
    const float* p = w + off + tid*16;
    #pragma unroll
    for (int j = 0; j < 4; j++) {
        float4 v = *(const float4*)(p + j*4);
        acc += fabsf(v.x) + fabsf(v.y) + fabsf(v.z) + fabsf(v.w);
    }
    red[tid] = acc; __syncthreads();
    for (int s = 128; s > 0; s >>= 1) { if (tid < s) red[tid] += red[tid+s]; __syncthreads(); }
    if (tid == 0) partial[blk] = red[0];
}

// ---------------- K1b: finalize 4 scales ----------------
__global__ __launch_bounds__(256) void absmean2_kernel(const float* __restrict__ partial, float* __restrict__ scales) {
    int m = blockIdx.x;
    __shared__ float red[256];
    int tid = threadIdx.x;
    red[tid] = partial[m*256 + tid]; __syncthreads();
    for (int s = 128; s > 0; s >>= 1) { if (tid < s) red[tid] += red[tid+s]; __syncthreads(); }
    if (tid == 0) scales[m] = fmaxf(red[0] / (float)(DIM_*DIM_), 1e-5f);
}

// ---------------- K2: ternary-quantize weights -> bf16 {-1,0,+1} ----------------
__global__ __launch_bounds__(256) void quant_w_kernel(const float* __restrict__ w, const float* __restrict__ scales,
                                                      unsigned short* __restrict__ wq) {
    int base = (blockIdx.x * 256 + threadIdx.x) * 8;
    float s = scales[base >> 20];
    float inv = 1.f / s;
    unsigned short out[8];
    float4 v0 = *(const float4*)(w + base);
    float4 v1 = *(const float4*)(w + base + 4);
    float t[8] = {v0.x, v0.y, v0.z, v0.w, v1.x, v1.y, v1.z, v1.w};
    #pragma unroll
    for (int j = 0; j < 8; j++) {
        float r = rintf(t[j] * inv);
        r = fminf(1.f, fmaxf(-1.f, r));
        out[j] = (r == 0.f) ? 0 : (r > 0.f ? 0x3F80 : 0xBF80);
    }
    *(int4*)(wq + base) = *(const int4*)out;
}

// ---------------- K3: per-row 8-bit quant of x (bf16 out) + gate ----------------
__global__ __launch_bounds__(256) void quant_x_gate_kernel(const float* __restrict__ x, const float* __restrict__ gw,
                                                           unsigned short* __restrict__ xqb, float* __restrict__ gate) {
    int row = blockIdx.x;
    const float* xr = x + (size_t)row * DIM_;
    unsigned short* qr = xqb + (size_t)row * DIM_;
    __shared__ float red[256];
    __shared__ float x12[12];
    int tid = threadIdx.x;
    float v[4];
    float mn = 1e30f, mx = -1e30f;
    #pragma unroll
    for (int i = 0; i < 4; i++) {
        v[i] = xr[i*256 + tid];
        mn = fminf(mn, v[i]); mx = fmaxf(mx, v[i]);
    }
    red[tid] = mn; __syncthreads();
    for (int s = 128; s > 0; s >>= 1) { if (tid < s) red[tid] = fminf(red[tid], red[tid+s]); __syncthreads(); }
    mn = red[0]; __syncthreads();
    red[tid] = mx; __syncthreads();
    for (int s = 128; s > 0; s >>= 1) { if (tid < s) red[tid] = fmaxf(red[tid], red[tid+s]); __syncthreads(); }
    mx = red[0]; __syncthreads();
    float p = fmaxf(mx, 1e-5f);
    float n = fminf(mn, -1e-5f);
    #pragma unroll
    for (int i = 0; i < 4; i++) {
        int gi = i*256 + tid;
        float xv = v[i];
        float sc = (xv >= 0.f) ? p : n;
        float q = rintf(xv / sc * 127.f) / 127.f * sc;
        qr[gi] = bf16r(q);
        if (gi < 12) x12[gi] = q;
    }
    __syncthreads();
    if (tid < H_) {
        float acc = 0.f;
        #pragma unroll
        for (int f = 0; f < 12; f++) acc += x12[f] * gw[tid*12 + f];
        gate[(size_t)row * H_ + tid] = 1.f / (1.f + expf(-acc));
    }
}

// ---------------- bf16 MFMA GEMM. BM = MT*32, BN = 128, BK = 64. OBF: bf16 output ----------------
template<int MT, bool OBF>
__global__ __launch_bounds__(256) void gemm_bf16_kernel(const unsigned short* __restrict__ A,
                                                        const unsigned short* __restrict__ Bm,
                                                        const float* __restrict__ sw, int sbase,
                                                        void* __restrict__ Cv, int M, int N, int K) {
    __shared__ __align__(16) unsigned short As[MT*32*64];
    __shared__ __align__(16) unsigned short Bs[128*64];
    int bm = blockIdx.y * (MT*32), bn = blockIdx.x * 128;
    int tid = threadIdx.x;
    int w = tid >> 6, l = tid & 63;
    int wr = w >> 1, wc = w & 1;
    int lg = l >> 4, lq = l & 15;
    f32x4_t acc[MT][4];
    #pragma unroll
    for (int mt = 0; mt < MT; mt++)
        #pragma unroll
        for (int nt = 0; nt < 4; nt++) acc[mt][nt] = (f32x4_t)0.f;

    for (int k0 = 0; k0 < K; k0 += 64) {
        #pragma unroll
        for (int i = 0; i < MT; i++) {
            int ob = (i*4 + w) << 10;
            int o  = ob + (l << 4);
            int row = o >> 7;
            int lcn = ((o >> 4) & 7) ^ (row & 7);
            gl16(A + (size_t)(bm+row)*K + k0 + lcn*8, (unsigned short*)As + (ob >> 1));
        }
        #pragma unroll
        for (int i = 0; i < 4; i++) {
            int ob = (i*4 + w) << 10;
            int o  = ob + (l << 4);
            int row = o >> 7;
            int lcn = ((o >> 4) & 7) ^ (row & 7);
            gl16(Bm + (size_t)(bn+row)*K + k0 + lcn*8, (unsigned short*)Bs + (ob >> 1));
        }
        __syncthreads();
        #pragma unroll
        for (int kk = 0; kk < 2; kk++) {
            bh8_t af[MT], bf[4];
            #pragma unroll
            for (int mt = 0; mt < MT; mt++) {
                int r = wr*(MT*16) + mt*16 + lq;
                int j = kk*4 + lg;
                af[mt] = *(const bh8_t*)(As + r*64 + (((j ^ (r & 7)))<<3));
            }
            #pragma unroll
            for (int nt = 0; nt < 4; nt++) {
                int r = wc*64 + nt*16 + lq;
                int j = kk*4 + lg;
                bf[nt] = *(const bh8_t*)(Bs + r*64 + (((j ^ (r & 7)))<<3));
            }
            #pragma unroll
            for (int mt = 0; mt < MT; mt++)
                #pragma unroll
                for (int nt = 0; nt < 4; nt++)
                    acc[mt][nt] = __builtin_amdgcn_mfma_f32_16x16x32_bf16(af[mt], bf[nt], acc[mt][nt], 0, 0, 0);
        }
        __syncthreads();
    }
    #pragma unroll
    for (int nt = 0; nt < 4; nt++) {
        int col = bn + wc*64 + nt*16 + lq;
        float s = sw[sbase + (col >> 10)];
        #pragma unroll
        for (int mt = 0; mt < MT; mt++) {
            int row = bm + wr*(MT*16) + mt*16 + lg*4;
            #pragma unroll
            for (int r = 0; r < 4; r++) {
                if constexpr (OBF)
                    ((unsigned short*)Cv)[(size_t)(row + r)*N + col] = bf16r(acc[mt][nt][r] * s);
                else
                    ((float*)Cv)[(size_t)(row + r)*N + col] = acc[mt][nt][r] * s;
            }
        }
    }
}

// ---------------- K5: rmsnorm/rotary/quant from bf16 QKV (wave-per-row, shfl, no LDS) ----------------
__global__ __launch_bounds__(256) void qkv_post_kernel(const unsigned short* __restrict__ qkvb,
                                                       const float* __restrict__ ve,
                                                       const float* __restrict__ lam,
                                                       const float* __restrict__ cosb, const float* __restrict__ sinb,
                                                       unsigned short* __restrict__ Qb, unsigned short* __restrict__ Kb,
                                                       unsigned short* __restrict__ Vb) {
    int bt = blockIdx.x;
    int b = bt >> 11, t = bt & (T_ - 1);
    int w = threadIdx.x >> 6, l = threadIdx.x & 63;
    const unsigned short* base = qkvb + (size_t)bt * E3_;
    float l0 = lam[0], l1 = lam[1];
    #pragma unroll
    for (int i = 0; i < 2; i++) {
        int h = w*2 + i;
        const unsigned short* row = base + (16 + h)*HD_;
        const float* ver = ve + (size_t)bt*DIM_ + h*HD_;
        unsigned short* dst = Vb + ((size_t)(b*H_+h)*T_ + t)*HD_;
        dst[l]      = bf16r(l0*b2f(row[l])    + l1*ver[l]);
        dst[l + 64] = bf16r(l0*b2f(row[l+64]) + l1*ver[l+64]);
    }
    float cc = cosb[(size_t)t*64 + l], ss = sinb[(size_t)t*64 + l];
    #pragma unroll
    for (int i = 0; i < 4; i++) {
        int part = w*4 + i;                 // 0..15
        const unsigned short* row = base + part*HD_;
        float x1 = b2f(row[l]), x2 = b2f(row[l+64]);
        float ssq = x1*x1 + x2*x2;
        #pragma unroll
        for (int off = 1; off < 64; off <<= 1) ssq += __shfl_xor(ssq, off);
        float rms = 1.0f / sqrtf(ssq / 128.0f + F32_EPS_);
        x1 *= rms; x2 *= rms;
        float o1 = x1*cc + x2*ss;
        float o2 = -x1*ss + x2*cc;
        float mn = fminf(o1, o2), mx = fmaxf(o1, o2);
        #pragma unroll
        for (int off = 1; off < 64; off <<= 1) {
            mn = fminf(mn, __shfl_xor(mn, off));
            mx = fmaxf(mx, __shfl_xor(mx, off));
        }
        float p = fmaxf(mx, 1e-5f);
        float n = fminf(mn, -1e-5f);
        float s1 = (o1 >= 0.f) ? p : n;
        float s2 = (o2 >= 0.f) ? p : n;
        float q1 = rintf(o1 / s1 * 127.f) / 127.f * s1;
        float q2 = rintf(o2 / s2 * 127.f) / 127.f * s2;
        if (part < 8) {
            unsigned short* dst = Qb + ((size_t)(b*H_+part)*T_ + t)*HD_;
            dst[l] = bf16r(QSC_ * q1); dst[l + 64] = bf16r(QSC_ * q2);
        } else {
            unsigned short* dst = Kb + ((size_t)(b*H_+part-8)*T_ + t)*HD_;
            dst[l] = bf16r(q1); dst[l + 64] = bf16r(q2);
        }
    }
}

// ---------------- K6: transpose V (bf16): Vb[bh][t][d] -> VT[bh][d][t] ----------------
__global__ __launch_bounds__(256) void transpose_v_kernel(const unsigned short* __restrict__ Vb,
                                                          unsigned short* __restrict__ VT) {
    int tt = blockIdx.x;
    int dt = blockIdx.y;
    int bh = blockIdx.z;
    __shared__ unsigned short L[64][80];
    int tid = threadIdx.x;
    #pragma unroll
    for (int i = 0; i < 2; i++) {
        int c = tid + i*256;
        int r = c >> 3, dc = c & 7;
        int4 v = *(const int4*)(Vb + ((size_t)bh*T_ + tt*64 + r)*HD_ + dt*64 + dc*8);
        *(int4*)(&L[r][dc*8]) = v;
    }
    __syncthreads();
    #pragma unroll
    for (int i = 0; i < 2; i++) {
        int c = tid + i*256;
        int r = c >> 3, tc = c & 7;
        unsigned short tmp[8];
        #pragma unroll
        for (int jj = 0; jj < 8; jj++) tmp[jj] = L[tc*8+jj][r];
        *(int4*)(VT + ((size_t)bh*HD_ + dt*64 + r)*T_ + tt*64 + tc*8) = *(const int4*)tmp;
    }
}

// ---------------- K7: flash attention, 4 waves = 2 qsub x 2 kv-streams, KVBLK=64, 64KB LDS ----------------
__global__ __launch_bounds__(256) void attn_kernel(const unsigned short* __restrict__ Qb,
                                                   const unsigned short* __restrict__ Kb,
                                                   const unsigned short* __restrict__ VT,
                                                   const float* __restrict__ gate,
                                                   unsigned short* __restrict__ Yb) {
    __shared__ __align__(16) unsigned char SMEM[65536];   // K[2]:2x16KB | V[2]:2x16KB
    int id = blockIdx.x;
    int bh = id & 15;
    int qi = id >> 4;
    int qt = (qi < 16) ? (31 - qi) : (qi - 16);           // pair big with small per CU
    int b = bh >> 3, h = bh & 7;
    int tid = threadIdx.x;
    int w = tid >> 6, l = tid & 63;
    int qsub = w >> 1, qq = w & 1;
    int hh = l >> 5, l5 = l & 31;
    int qrow = qsub*32 + l5;
    int qg = qt*64 + qrow;

    const unsigned short* Kbase = Kb + (size_t)bh*T_*HD_;
    const unsigned short* Vbase = VT + (size_t)bh*HD_*T_;
    const unsigned short* Qg = Qb + ((size_t)bh*T_ + (size_t)qt*64) * HD_;

    bh8_t qf[8];
    #pragma unroll
    for (int ks = 0; ks < 8; ks++)
        qf[ks] = *(const bh8_t*)(Qg + (size_t)qrow*HD_ + ks*16 + hh*8);

    int nr = qt + 1;

    f32x16_t o0 = (f32x16_t)0.f, o1 = (f32x16_t)0.f, o2 = (f32x16_t)0.f, o3 = (f32x16_t)0.f;
    float mrun = -1e20f, lrun = 0.f;

    // K: 4-bit XOR swizzle (16-chunk rows, 2-way = free); V: 3-bit (8-chunk rows)
#define STAGE(BI, J) { \
    unsigned short* kb_ = (unsigned short*)(SMEM + (BI)*16384); \
    unsigned short* vb_ = (unsigned short*)(SMEM + 32768 + (BI)*16384); \
    _Pragma("unroll") \
    for (int i_ = 0; i_ < 4; i_++) { \
        int ob_ = (i_*4 + w) << 10; \
        int o_  = ob_ + (l << 4); \
        int rk_ = o_ >> 8; \
        int lk_ = ((o_ >> 4) & 15) ^ (rk_ & 15); \
        gl16(Kbase + (size_t)((J)*64 + rk_)*HD_ + lk_*8, kb_ + (ob_ >> 1)); \
        int rv_ = o_ >> 7; \
        int lv_ = ((o_ >> 4) & 7) ^ (rv_ & 7); \
        gl16(Vbase + (size_t)rv_*T_ + (J)*64 + lv_*8, vb_ + (ob_ >> 1)); \
    } }

    STAGE(0, 0);
    for (int j = 0; j < nr; j++) {
        if (j + 1 < nr) {
            STAGE((j+1) & 1, j+1);
            asm volatile("s_waitcnt vmcnt(8)" ::: "memory");
        } else {
            asm volatile("s_waitcnt vmcnt(0)" ::: "memory");
        }
        __builtin_amdgcn_s_barrier();
        asm volatile("" ::: "memory");
        const unsigned short* kb = (const unsigned short*)(SMEM + (j&1)*16384);
        const unsigned short* vb = (const unsigned short*)(SMEM + 32768 + (j&1)*16384);
        int kvb = j*64 + qq*32;
        if (kvb <= qt*64 + qsub*32 + 31) {
            // S^T(32k x 32q) = K_half @ Q^T   (log2 domain: Q pre-scaled by 0.12*log2e)
            f32x16_t s = (f32x16_t)0.f;
            int krow = qq*32 + l5;
            __builtin_amdgcn_s_setprio(1);
            #pragma unroll
            for (int ks = 0; ks < 8; ks++) {
                int c = (ks*2 + hh) ^ (krow & 15);
                bh8_t kf = *(const bh8_t*)(kb + krow*128 + c*8);
                s = __builtin_amdgcn_mfma_f32_32x32x16_bf16(kf, qf[ks], s, 0, 0, 0);
            }
            __builtin_amdgcn_s_setprio(0);
            if (kvb + 31 > qt*64 + qsub*32) {
                #pragma unroll
                for (int r = 0; r < 16; r++) {
                    int key = kvb + (r & 3) + 8*(r >> 2) + 4*hh;
                    if (key > qg) s[r] = -1e30f;
                }
            }
            // online softmax, defer-max THR=8 (P bounded by 2^8)
            float t8[8], t4[4];
            #pragma unroll
            for (int r = 0; r < 8; r++) t8[r] = fmaxf(s[2*r], s[2*r+1]);
            #pragma unroll
            for (int r = 0; r < 4; r++) t4[r] = fmaxf(t8[2*r], t8[2*r+1]);
            float tm = fmaxf(fmaxf(t4[0], t4[1]), fmaxf(t4[2], t4[3]));
            tm = fmaxf(tm, __shfl_xor(tm, 32));
            if (!__all(tm - mrun <= 8.f)) {
                float mnew = fmaxf(mrun, tm);
                float scf = __builtin_amdgcn_exp2f(mrun - mnew);
                lrun *= scf;
                o0 *= scf; o1 *= scf; o2 *= scf; o3 *= scf;
                mrun = mnew;
            }
            float p[16];
            #pragma unroll
            for (int r = 0; r < 16; r++) p[r] = __builtin_amdgcn_exp2f(s[r] - mrun);
            #pragma unroll
            for (int r = 0; r < 8; r++) t8[r] = p[2*r] + p[2*r+1];
            #pragma unroll
            for (int r = 0; r < 4; r++) t4[r] = t8[2*r] + t8[2*r+1];
            float ls = (t4[0] + t4[1]) + (t4[2] + t4[3]);
            ls += __shfl_xor(ls, 32);
            lrun += ls;
            // pack P -> bf16 B-frags (v_cvt_pk) via lane<->lane+32 exchange
            unsigned u0 = cvtpk(p[0], p[1]),   u1 = cvtpk(p[2], p[3]);
            unsigned u2 = cvtpk(p[4], p[5]),   u3 = cvtpk(p[6], p[7]);
            unsigned u4 = cvtpk(p[8], p[9]),   u5 = cvtpk(p[10], p[11]);
            unsigned u6 = cvtpk(p[12], p[13]), u7 = cvtpk(p[14], p[15]);
            unsigned x0 = (unsigned)__shfl_xor((int)u0, 32), x1 = (unsigned)__shfl_xor((int)u1, 32);
            unsigned x2 = (unsigned)__shfl_xor((int)u2, 32), x3 = (unsigned)__shfl_xor((int)u3, 32);
            unsigned x4 = (unsigned)__shfl_xor((int)u4, 32), x5 = (unsigned)__shfl_xor((int)u5, 32);
            unsigned x6 = (unsigned)__shfl_xor((int)u6, 32), x7 = (unsigned)__shfl_xor((int)u7, 32);
            union { bh8_t v; unsigned uu[4]; } B0, B1;
            B0.uu[0] = hh ? x2 : u0;  B0.uu[1] = hh ? x3 : u1;
            B0.uu[2] = hh ? u2 : x0;  B0.uu[3] = hh ? u3 : x1;
            B1.uu[0] = hh ? x6 : u4;  B1.uu[1] = hh ? x7 : u5;
            B1.uu[2] = hh ? u6 : x4;  B1.uu[3] = hh ? u7 : x5;
            // O^T(128d x 32q) += V^T_half @ P^T
            __builtin_amdgcn_s_setprio(1);
#define PV_STEP(DT, OACC) { \
    int vrow = DT*32 + l5; \
    bh8_t vf0 = *(const bh8_t*)(vb + vrow*64 + (((qq*4 + hh) ^ (vrow & 7))<<3)); \
    OACC = __builtin_amdgcn_mfma_f32_32x32x16_bf16(vf0, B0.v, OACC, 0, 0, 0); \
    bh8_t vf1 = *(const bh8_t*)(vb + vrow*64 + (((qq*4 + 2 + hh) ^ (vrow & 7))<<3)); \
    OACC = __builtin_amdgcn_mfma_f32_32x32x16_bf16(vf1, B1.v, OACC, 0, 0, 0); }
            PV_STEP(0, o0) PV_STEP(1, o1) PV_STEP(2, o2) PV_STEP(3, o3)
#undef PV_STEP
            __builtin_amdgcn_s_setprio(0);
        }
        asm volatile("s_waitcnt lgkmcnt(0)" ::: "memory");
        __builtin_amdgcn_s_barrier();
        asm volatile("" ::: "memory");
    }

    // ---- 2-way stream merge per qsub (LDS reuse), then epilogue ----
    f32x16_t oA[4] = {o0, o1, o2, o3};
    float* OB = (float*)SMEM;
    float* ML = (float*)(SMEM + 32768);
    unsigned short* YS = (unsigned short*)(SMEM + 33280);
    if (qq != 0) {
        float* obuf = OB + (size_t)qsub * 4096;
        #pragma unroll
        for (int dt = 0; dt < 4; dt++)
            #pragma unroll
            for (int g = 0; g < 4; g++) {
                f32x4_t v4;
                #pragma unroll
                for (int e = 0; e < 4; e++) v4[e] = oA[dt][g*4+e];
                int ch = (dt*4 + g) ^ (l & 7);
                *(f32x4_t*)(obuf + l*64 + ch*4) = v4;
            }
        if (hh == 0) {
            ML[(qsub*32 + l5)*2]     = mrun;
            ML[(qsub*32 + l5)*2 + 1] = lrun;
        }
    }
    __syncthreads();
    if (qq == 0) {
        float mb = ML[(qsub*32 + l5)*2];
        float lb = ML[(qsub*32 + l5)*2 + 1];
        float mN = fmaxf(mrun, mb);
        float fa = __builtin_amdgcn_exp2f(mrun - mN), fb = __builtin_amdgcn_exp2f(mb - mN);
        const float* obuf = OB + (size_t)qsub * 4096;
        #pragma unroll
        for (int dt = 0; dt < 4; dt++)
            #pragma unroll
            for (int g = 0; g < 4; g++) {
                int ch = (dt*4 + g) ^ (l & 7);
                f32x4_t v4 = *(const f32x4_t*)(obuf + l*64 + ch*4);
                #pragma unroll
                for (int e = 0; e < 4; e++)
                    oA[dt][g*4+e] = oA[dt][g*4+e]*fa + v4[e]*fb;
            }
        lrun = lrun*fa + lb*fb;
        float gv = gate[((size_t)b*T_ + (size_t)qg)*H_ + h];
        float inv = gv / lrun;
        #pragma unroll
        for (int dt = 0; dt < 4; dt++)
            #pragma unroll
            for (int g = 0; g < 4; g++) {
                unsigned short pk4[4];
                #pragma unroll
                for (int e = 0; e < 4; e++) pk4[e] = bf16r(oA[dt][g*4+e] * inv);
                int ch = (dt*4 + g) ^ (qrow & 7);
                *(us4_t*)(YS + (size_t)qrow*128 + ch*8 + hh*4) = *(const us4_t*)pk4;
            }
    }
    __syncthreads();
    #pragma unroll
    for (int i = 0; i < 4; i++) {
        int idx = tid + i*256;
        int r = idx >> 4, scn = idx & 15;
        int lcn = scn ^ (r & 7);
        int4 v = *(const int4*)(YS + (size_t)r*128 + scn*8);
        *(int4*)(Yb + (size_t)(b*T_ + qt*64 + r)*DIM_ + h*HD_ + lcn*8) = v;
    }
#undef STAGE
}

extern "C" void kernel_launch(void* const* d_in, const int* in_sizes, int n_in,
                              void* d_out, int out_size, void* d_ws, size_t ws_size,
                              hipStream_t stream) {
    const float* x    = (const float*)d_in[0];
    const float* ve   = (const float*)d_in[1];
    const float* lam  = (const float*)d_in[2];
    const float* cosb = (const float*)d_in[3];
    const float* sinb = (const float*)d_in[4];
    const float* qkvo = (const float*)d_in[5];
    const float* gw   = (const float*)d_in[6];

    char* ws = (char*)d_ws;
    float* scales  = (float*)ws;
    float* partial = scales + 16;
    unsigned short* WQb  = (unsigned short*)(ws + (1<<13));           // 8 MB
    unsigned short* XQb  = WQb + (size_t)4*DIM_*DIM_;                 // 8 MB
    unsigned short* QKVb = XQb + (size_t)BT_*DIM_;                    // 24 MB (bf16)
    float* GT = (float*)(QKVb + (size_t)BT_*E3_);                     // 128 KB
    unsigned short* Qb = (unsigned short*)(GT + (size_t)BT_*H_);      // 8 MB
    unsigned short* Kb = Qb + (size_t)B_*H_*T_*HD_;
    unsigned short* VT = Kb + (size_t)B_*H_*T_*HD_;
    unsigned short* Vb = VT + (size_t)B_*H_*T_*HD_;
    unsigned short* Yb = QKVb;                 // reuse (dead after qkv_post)

    absmean1_kernel<<<1024, 256, 0, stream>>>(qkvo, partial);
    absmean2_kernel<<<4, 256, 0, stream>>>(partial, scales);
    quant_w_kernel<<<(4*DIM_*DIM_)/(256*8), 256, 0, stream>>>(qkvo, scales, WQb);
    quant_x_gate_kernel<<<BT_, 256, 0, stream>>>(x, gw, XQb, GT);
    gemm_bf16_kernel<4, true><<<dim3(E3_/128, BT_/128), 256, 0, stream>>>(XQb, WQb, scales, 0, QKVb, BT_, E3_, DIM_);
    qkv_post_kernel<<<BT_, 256, 0, stream>>>(QKVb, ve, lam, cosb, sinb, Qb, Kb, Vb);
    transpose_v_kernel<<<dim3(T_/64, HD_/64, B_*H_), 256, 0, stream>>>(Vb, VT);
    attn_kernel<<<512, 256, 0, stream>>>(Qb, Kb, VT, GT, Yb);
    gemm_bf16_kernel<2, false><<<dim3(DIM_/128, BT_/64), 256, 0, stream>>>(Yb, WQb + (size_t)3*DIM_*DIM_, scales, 3,
                                                                           (float*)d_out, BT_, DIM_, DIM_);
}